// Round 1
// baseline (194.961 us; speedup 1.0000x reference)
//
#include <hip/hip_runtime.h>
#include <hip/hip_bf16.h>

// B=2, S=2048, D=1024, H=16, DK=64, THETA=10000
// Inputs fp32 (positions int32): x[2,2048,1024], token_positions[2048],
// Wq,Wk,Wv,Wo [1024,1024].  Output fp32 [2,2048,1024].
// proj: y[b,s,o] = sum_d x[b,s,d] * W[o,d]

typedef __attribute__((ext_vector_type(8))) short short8;   // 8 bf16 = 4 VGPRs
typedef __attribute__((ext_vector_type(4))) float floatx4;  // MFMA accumulator

static __device__ __forceinline__ unsigned short f2bf(float f) {
  __hip_bfloat16 h = __float2bfloat16(f);
  return *(unsigned short*)&h;
}

// pack 2 floats -> 2 bf16 in one u32 (half-up rounding + v_perm byte pick).
// low ushort = bf16(a), high ushort = bf16(b). Finite inputs only.
static __device__ __forceinline__ unsigned int pk2bf(float a, float b) {
  unsigned int ua = __float_as_uint(a) + 0x8000u;
  unsigned int ub = __float_as_uint(b) + 0x8000u;
  return __builtin_amdgcn_perm(ub, ua, 0x07060302u);
}

// raw v_exp_f32 (2^x), single VALU transcendental; s_nop covers the
// trans->VALU dependency wait state.
static __device__ __forceinline__ float fexp2(float x) {
  float r;
  asm("v_exp_f32 %0, %1\n\ts_nop 0" : "=v"(r) : "v"(x));
  return r;
}

// async global->LDS DMA, 16 B per lane; lds base must be wave-uniform,
// HW writes lane i at ldsbase + i*16.
static __device__ __forceinline__ void gl2lds16(const unsigned short* g,
                                                unsigned short* l) {
  __builtin_amdgcn_global_load_lds(
      (const __attribute__((address_space(1))) void*)g,
      (__attribute__((address_space(3))) void*)l, 16, 0, 0);
}

// ---------------------------------------------------------------------------
// fp32 -> bf16 conversion for all 5 tensors + RoPE table gen, one launch.
// blockIdx.y: 0=x 1=Wq 2=Wk 3=Wv 4=Wo 5=rope tables
// ---------------------------------------------------------------------------
__global__ __launch_bounds__(256) void cvt_all(
    const float4* __restrict__ x,  const float4* __restrict__ wq,
    const float4* __restrict__ wk, const float4* __restrict__ wv,
    const float4* __restrict__ wo,
    ushort4* __restrict__ xb,  ushort4* __restrict__ wqb,
    ushort4* __restrict__ wkb, ushort4* __restrict__ wvb,
    ushort4* __restrict__ wob,
    const int* __restrict__ tokpos,
    float* __restrict__ ctab, float* __restrict__ stab) {
  int t = blockIdx.y;
  int i = blockIdx.x * 256 + threadIdx.x;
  if (t == 5) {
    if (i < 65536) {     // 2048 positions x 32 pair-freqs
      int s = i >> 5, f = i & 31;
      float inv = expf(-9.210340371976184f * (float)(2 * f) / 64.0f);
      float ang = (float)tokpos[s] * inv;
      ctab[i] = cosf(ang);
      stab[i] = sinf(ang);
    }
    return;
  }
  const float4* s = (t == 0) ? x : (t == 1) ? wq : (t == 2) ? wk : (t == 3) ? wv : wo;
  ushort4* d = (t == 0) ? xb : (t == 1) ? wqb : (t == 2) ? wkb : (t == 3) ? wvb : wob;
  int n4 = (t == 0) ? 1048576 : 262144;
  if (i < n4) {
    float4 v = s[i];
    ushort4 o;
    o.x = f2bf(v.x); o.y = f2bf(v.y); o.z = f2bf(v.z); o.w = f2bf(v.w);
    d[i] = o;
  }
}

// ---------------------------------------------------------------------------
// 128x128-tile GEMM body, DOUBLE-BUFFERED (R10): single barrier per K-step.
// Previous structure (stage kt -> sync -> compute kt -> sync) exposed the
// full L2/L3 staging latency every iter (MfmaUtil 17.7%, ~2700 cyc/iter vs
// ~1464 for the same structure at 4k^3).  Now: STAGE(kt+1, slot^1) issued
// BEFORE compute(kt, slot); the single end-of-iter __syncthreads provides
// the vmcnt(0)+lgkmcnt(0) drain + barrier that makes the swap race-free:
//  - my stage writes to slot^1 land (vmcnt(0)) and become visible (barrier)
//    before any wave reads slot^1 next iter;
//  - all ds_reads of slot finish (lgkmcnt(0)) before slot is overwritten.
// Staging/fragment addressing unchanged: global_load_lds width=16 into
// UNPADDED [128][64] tiles with XOR chunk swizzle (LDS[r][c] holds global
// chunk c^(r&7); reads fetch chunk (4ks+quad)^(l15&7) -> conflict-free,
// SQ_LDS_BANK_CONFLICT measured 0).  LDS 64 KiB -> 2 blocks/CU resident.
// ---------------------------------------------------------------------------
#define GEMM128_BODY(Aptr, Wptr, m0, n0)                                        \
  __shared__ __align__(16) unsigned short lA[2][128 * 64];                      \
  __shared__ __align__(16) unsigned short lB[2][128 * 64];                      \
  int tid = threadIdx.x;                                                        \
  int wave = tid >> 6, lane = tid & 63;                                         \
  int wm = wave >> 1, wn = wave & 1;                                            \
  int l15 = lane & 15, quad = lane >> 4;                                        \
  int srow = wave * 32 + (lane >> 3);  /* staging row (+p*8) */                 \
  int sch = lane & 7;                  /* staging 16B-chunk  */                 \
  int fsw = l15 & 7;                   /* fragment-read swizzle */              \
  floatx4 acc[4][4];                                                            \
  _Pragma("unroll") for (int m = 0; m < 4; ++m)                                 \
      _Pragma("unroll") for (int n = 0; n < 4; ++n)                             \
          acc[m][n] = (floatx4){0.f, 0.f, 0.f, 0.f};                            \
  _Pragma("unroll") for (int p = 0; p < 4; ++p) {                               \
    int r = srow + p * 8;                                                       \
    int g = sch ^ (r & 7);                                                      \
    gl2lds16(Aptr + (size_t)(m0 + r) * 1024 + g * 8,                            \
             lA[0] + (wave * 32 + p * 8) * 64);                                 \
    gl2lds16(Wptr + (size_t)(n0 + r) * 1024 + g * 8,                            \
             lB[0] + (wave * 32 + p * 8) * 64);                                 \
  }                                                                             \
  __syncthreads();                                                              \
  for (int kt = 0; kt < 16; ++kt) {                                             \
    int cur = kt & 1;                                                           \
    if (kt < 15) { /* prefetch next K-tile into other slot (hidden by MFMA) */  \
      _Pragma("unroll") for (int p = 0; p < 4; ++p) {                           \
        int r = srow + p * 8;                                                   \
        int g = sch ^ (r & 7);                                                  \
        gl2lds16(Aptr + (size_t)(m0 + r) * 1024 + (kt + 1) * 64 + g * 8,        \
                 lA[cur ^ 1] + (wave * 32 + p * 8) * 64);                       \
        gl2lds16(Wptr + (size_t)(n0 + r) * 1024 + (kt + 1) * 64 + g * 8,        \
                 lB[cur ^ 1] + (wave * 32 + p * 8) * 64);                       \
      }                                                                         \
    }                                                                           \
    _Pragma("unroll") for (int ks = 0; ks < 2; ++ks) {                          \
      short8 af[4], bf[4];                                                      \
      _Pragma("unroll") for (int m = 0; m < 4; ++m)                             \
          af[m] = *(const short8*)(lA[cur] + (wm * 64 + m * 16 + l15) * 64 +    \
                                   (((ks * 4 + quad) ^ fsw) * 8));              \
      _Pragma("unroll") for (int n = 0; n < 4; ++n)                             \
          bf[n] = *(const short8*)(lB[cur] + (wn * 64 + n * 16 + l15) * 64 +    \
                                   (((ks * 4 + quad) ^ fsw) * 8));              \
      _Pragma("unroll") for (int m = 0; m < 4; ++m)                             \
          _Pragma("unroll") for (int n = 0; n < 4; ++n)                         \
              acc[m][n] = __builtin_amdgcn_mfma_f32_16x16x32_bf16(              \
                  af[m], bf[n], acc[m][n], 0, 0, 0);                            \
    }                                                                           \
    __syncthreads();                                                            \
  }

// ---------------------------------------------------------------------------
// QKV projection, tiled MFMA GEMM + fused RoPE epilogue.
// Q pre-scaled by (1/sqrt(64))*log2(e) so attention uses raw v_exp_f32.
// Q,K bf16 [bh][s][64]; V transposed [bh][d][2048].
// ---------------------------------------------------------------------------
__global__ __launch_bounds__(256) void qkv_mfma(
    const unsigned short* __restrict__ X,
    const unsigned short* __restrict__ Wq,
    const unsigned short* __restrict__ Wk,
    const unsigned short* __restrict__ Wv,
    const float* __restrict__ ctab, const float* __restrict__ stab,
    unsigned short* __restrict__ Qo, unsigned short* __restrict__ Ko,
    unsigned short* __restrict__ Vo) {
  int mat = blockIdx.z;  // 0=q 1=k 2=v
  const unsigned short* W = (mat == 0) ? Wq : ((mat == 1) ? Wk : Wv);
  unsigned short* Out = (mat == 0) ? Qo : ((mat == 1) ? Ko : Vo);
  int m0 = blockIdx.x * 128, n0 = blockIdx.y * 128;

  GEMM128_BODY(X, W, m0, n0)

#pragma unroll
  for (int n = 0; n < 4; ++n) {
    int col = n0 + wn * 64 + n * 16 + l15;  // 0..1023
    int h = col >> 6;
    int d = col & 63;
    int pi = d >> 1;
    bool odd = (d & 1) != 0;
    size_t hb = (size_t)h * 2048 * 64;
#pragma unroll
    for (int m = 0; m < 4; ++m) {
      int row0 = m0 + wm * 64 + m * 16 + quad * 4;  // rows row0..row0+3
      int b = row0 >> 11;
      int s0 = row0 & 2047;
      size_t base = (size_t)b * 16 * 2048 * 64 + hb;
      if (mat == 2) {
        // V: packed b64 store along s (transposed layout [d][s])
        ushort4 pv;
        pv.x = f2bf(acc[m][n][0]);
        pv.y = f2bf(acc[m][n][1]);
        pv.z = f2bf(acc[m][n][2]);
        pv.w = f2bf(acc[m][n][3]);
        *(ushort4*)(Out + base + (size_t)d * 2048 + s0) = pv;
      } else {
#pragma unroll
        for (int i = 0; i < 4; ++i) {
          int s = s0 + i;
          float v = acc[m][n][i];
          float p = __shfl_xor(v, 1);
          float c = ctab[s * 32 + pi];
          float sn = stab[s * 32 + pi];
          float res = odd ? fmaf(p, sn, v * c) : fmaf(v, c, -p * sn);
          if (mat == 0) res *= 0.1803368801111204f;  // 0.125 * log2(e)
          Out[base + (size_t)s * 64 + d] = f2bf(res);
        }
      }
    }
  }
}

// ---------------------------------------------------------------------------
// Output projection: out = Oc @ Wo^T.  64x128 tiles -> 512 blocks (2/CU).
// Same double-buffered single-barrier K-loop as GEMM128 (R10); LDS 48 KiB
// -> 3 blocks/CU by LDS.  fp32 store.
// ---------------------------------------------------------------------------
__global__ __launch_bounds__(256) void oproj_mfma(
    const unsigned short* __restrict__ A, const unsigned short* __restrict__ Wo,
    float* __restrict__ Out) {
  __shared__ __align__(16) unsigned short lA[2][64 * 64];
  __shared__ __align__(16) unsigned short lB[2][128 * 64];
  int tid = threadIdx.x;
  int wave = tid >> 6, lane = tid & 63;
  int l15 = lane & 15, quad = lane >> 4;
  int rsub = lane >> 3, sch = lane & 7;
  int fsw = l15 & 7;
  int m0 = blockIdx.x * 64, n0 = blockIdx.y * 128;

  floatx4 acc[4][2];
#pragma unroll
  for (int m = 0; m < 4; ++m)
#pragma unroll
    for (int n = 0; n < 2; ++n) acc[m][n] = (floatx4){0.f, 0.f, 0.f, 0.f};

  // prologue: stage kt=0 into slot 0
#pragma unroll
  for (int p = 0; p < 2; ++p) {
    int r = wave * 16 + p * 8 + rsub;
    int g = sch ^ (r & 7);
    gl2lds16(A + (size_t)(m0 + r) * 1024 + g * 8, lA[0] + (wave * 16 + p * 8) * 64);
  }
#pragma unroll
  for (int p = 0; p < 4; ++p) {
    int r = wave * 32 + p * 8 + rsub;
    int g = sch ^ (r & 7);
    gl2lds16(Wo + (size_t)(n0 + r) * 1024 + g * 8, lB[0] + (wave * 32 + p * 8) * 64);
  }
  __syncthreads();

  for (int kt = 0; kt < 16; ++kt) {
    int cur = kt & 1;
    if (kt < 15) {  // prefetch next K-tile into other slot
#pragma unroll
      for (int p = 0; p < 2; ++p) {
        int r = wave * 16 + p * 8 + rsub;
        int g = sch ^ (r & 7);
        gl2lds16(A + (size_t)(m0 + r) * 1024 + (kt + 1) * 64 + g * 8,
                 lA[cur ^ 1] + (wave * 16 + p * 8) * 64);
      }
#pragma unroll
      for (int p = 0; p < 4; ++p) {
        int r = wave * 32 + p * 8 + rsub;
        int g = sch ^ (r & 7);
        gl2lds16(Wo + (size_t)(n0 + r) * 1024 + (kt + 1) * 64 + g * 8,
                 lB[cur ^ 1] + (wave * 32 + p * 8) * 64);
      }
    }
#pragma unroll
    for (int ks = 0; ks < 2; ++ks) {
      int slot = ((ks * 4 + quad) ^ fsw) * 8;
      short8 af[4], bf[2];
#pragma unroll
      for (int m = 0; m < 4; ++m)
        af[m] = *(const short8*)(lA[cur] + (m * 16 + l15) * 64 + slot);
#pragma unroll
      for (int n = 0; n < 2; ++n)
        bf[n] = *(const short8*)(lB[cur] + (wave * 32 + n * 16 + l15) * 64 + slot);
#pragma unroll
      for (int m = 0; m < 4; ++m)
#pragma unroll
        for (int n = 0; n < 2; ++n)
          acc[m][n] = __builtin_amdgcn_mfma_f32_16x16x32_bf16(
              af[m], bf[n], acc[m][n], 0, 0, 0);
    }
    __syncthreads();
  }

#pragma unroll
  for (int m = 0; m < 4; ++m) {
#pragma unroll
    for (int n = 0; n < 2; ++n) {
      int col = n0 + wave * 32 + n * 16 + l15;
#pragma unroll
      for (int i = 0; i < 4; ++i) {
        int row = m0 + m * 16 + quad * 4 + i;
        Out[(size_t)row * 1024 + col] = acc[m][n][i];
      }
    }
  }
}

// ---------------------------------------------------------------------------
// Flash attention: R8 shape (256 thr / 4 waves / 16 q per wave, 16 waves/CU)
// + R9's VALU cuts (raw v_exp_f32, v_perm bf16 packing).
// Transposed-score form: per-lane q softmax (in-lane tree + 2 shfl_xor).
// K/V LDS: unpadded stride-64 with XOR chunk swizzle (conflict-free).
// Register-prefetch double buffering for K/V staging.
// Balance swizzle: co-resident blocks {id,id+256,id+512,id+768} get qtiles
// {x, 31-x, (15-x)&31, (16+x)&31} -> 66 tile-iters per CU for every x.
// ---------------------------------------------------------------------------
#define LPS 72  // lP row stride

__global__ __launch_bounds__(256) void attn_flash(
    const unsigned short* __restrict__ Q, const unsigned short* __restrict__ K,
    const unsigned short* __restrict__ Vt, unsigned short* __restrict__ Oc) {
  __shared__ __align__(16) unsigned short lK[64 * 64];   // [kj][d] swizzled
  __shared__ __align__(16) unsigned short lV[64 * 64];   // [d][kj] swizzled
  __shared__ unsigned short lP[4][16 * LPS];             // per-wave [q][kj]

  int tid = threadIdx.x;
  int wave = tid >> 6, lane = tid & 63;
  int l15 = lane & 15, quad = lane >> 4;

  int xb_ = blockIdx.x;          // 0..31
  int yb_ = blockIdx.y;          // 0..31
  int jb = yb_ >> 3, ib = yb_ & 7;
  int qtile;
  if (jb == 0)      qtile = xb_;
  else if (jb == 1) qtile = 31 - xb_;
  else if (jb == 2) qtile = (15 - xb_) & 31;
  else              qtile = (16 + xb_) & 31;
  int bh = ib * 4 + jb;

  size_t base = (size_t)bh * 2048 * 64;
  int qbase = qtile * 64;

  // Q rows as B-operand fragments (B[k=d][n=q]); q = wavebase + l15
  const unsigned short* qrow = Q + base + (size_t)(qbase + wave * 16 + l15) * 64;
  short8 qb0 = *(const short8*)(qrow + quad * 8);
  short8 qb1 = *(const short8*)(qrow + 32 + quad * 8);

  floatx4 o[4];          // O^T[d = n*16+quad*4+reg][q = l15]
  float m_i = -1e30f, l_i = 0.f;   // per-lane softmax state (q = l15)
#pragma unroll
  for (int n = 0; n < 4; ++n) o[n] = (floatx4){0.f, 0.f, 0.f, 0.f};

  // staging: thread covers rows r0,r1 (r1=r0+32, same &7), global chunk g
  int r0 = tid >> 3, g = tid & 7;
  int r1 = r0 + 32;
  int e0 = g * 8;                       // global element offset of chunk g
  int sl = (g ^ (r0 & 7)) * 8;          // swizzled LDS slot (element offset)
  int fsw = l15 & 7;                    // fragment-read swizzle
  int c0 = (quad ^ fsw) * 8;            // slot of global chunk quad
  int c1 = ((quad + 4) ^ fsw) * 8;      // slot of global chunk quad+4

  // prefetch kt=0
  const unsigned short* kp = K + base;
  const unsigned short* vp = Vt + base;
  short8 pk0 = *(const short8*)(kp + r0 * 64 + e0);
  short8 pk1 = *(const short8*)(kp + r1 * 64 + e0);
  short8 pv0 = *(const short8*)(vp + (size_t)r0 * 2048 + e0);
  short8 pv1 = *(const short8*)(vp + (size_t)r1 * 2048 + e0);

  for (int kt = 0; kt <= qtile; ++kt) {
    __syncthreads();   // all waves done reading lK/lV from previous iter
    *(short8*)(lK + r0 * 64 + sl) = pk0;
    *(short8*)(lK + r1 * 64 + sl) = pk1;
    *(short8*)(lV + r0 * 64 + sl) = pv0;
    *(short8*)(lV + r1 * 64 + sl) = pv1;
    __syncthreads();

    if (kt < qtile) {  // prefetch next tile; consumed at next iter's LDS write
      const unsigned short* kn = K + base + (size_t)(kt + 1) * 4096;
      const unsigned short* vn = Vt + base + (kt + 1) * 64;
      pk0 = *(const short8*)(kn + r0 * 64 + e0);
      pk1 = *(const short8*)(kn + r1 * 64 + e0);
      pv0 = *(const short8*)(vn + (size_t)r0 * 2048 + e0);
      pv1 = *(const short8*)(vn + (size_t)r1 * 2048 + e0);
    }

    // ---- S^T = K·Q^T : sc[sub][i] is score for kpos = sub*16+quad*4+i, q=l15
    float sc[4][4];
#pragma unroll
    for (int sub = 0; sub < 4; ++sub) {
      const unsigned short* kr = lK + (sub * 16 + l15) * 64;
      short8 a0 = *(const short8*)(kr + c0);
      short8 a1 = *(const short8*)(kr + c1);
      floatx4 s = {0.f, 0.f, 0.f, 0.f};
      s = __builtin_amdgcn_mfma_f32_16x16x32_bf16(a0, qb0, s, 0, 0, 0);
      s = __builtin_amdgcn_mfma_f32_16x16x32_bf16(a1, qb1, s, 0, 0, 0);
#pragma unroll
      for (int i = 0; i < 4; ++i) sc[sub][i] = s[i];
    }

    // ---- causal mask (diagonal tile only): k-within > q-within
    if (kt == qtile) {
      int qin = wave * 16 + l15;
#pragma unroll
      for (int sub = 0; sub < 4; ++sub)
#pragma unroll
        for (int i = 0; i < 4; ++i)
          if (sub * 16 + quad * 4 + i > qin) sc[sub][i] = -1e30f;
    }

    // ---- online softmax (log2 domain): in-lane tree + 2 cross-quad shuffles
    float mb = sc[0][0];
#pragma unroll
    for (int sub = 0; sub < 4; ++sub)
#pragma unroll
      for (int i = 0; i < 4; ++i) mb = fmaxf(mb, sc[sub][i]);
    mb = fmaxf(mb, __shfl_xor(mb, 16));
    mb = fmaxf(mb, __shfl_xor(mb, 32));

    float mn = fmaxf(m_i, mb);
    float al = fexp2(m_i - mn);
    m_i = mn;
    float rs = 0.f;
#pragma unroll
    for (int sub = 0; sub < 4; ++sub)
#pragma unroll
      for (int i = 0; i < 4; ++i) {
        float p = fexp2(sc[sub][i] - mn);
        sc[sub][i] = p;
        rs += p;
      }
    rs += __shfl_xor(rs, 16);
    rs += __shfl_xor(rs, 32);
    l_i = l_i * al + rs;

    // per-lane rescale of O^T columns (q = l15 matches softmax state)
#pragma unroll
    for (int n = 0; n < 4; ++n) {
      o[n][0] *= al; o[n][1] *= al; o[n][2] *= al; o[n][3] *= al;
    }

    // ---- P^T -> lP rows [q][k], packed pairs via v_perm
    unsigned short* pw = lP[wave] + l15 * LPS;
#pragma unroll
    for (int sub = 0; sub < 4; ++sub) {
      uint2 w;
      w.x = pk2bf(sc[sub][0], sc[sub][1]);
      w.y = pk2bf(sc[sub][2], sc[sub][3]);
      *(uint2*)(pw + sub * 16 + quad * 4) = w;
    }

    const unsigned short* pr = lP[wave] + l15 * LPS + quad * 8;
    short8 pa0 = *(const short8*)(pr);
    short8 pa1 = *(const short8*)(pr + 32);

    // ---- O^T += V^T·P^T : A = lV rows (d), B = lP rows (q)
#pragma unroll
    for (int n = 0; n < 4; ++n) {
      const unsigned short* vr = lV + (n * 16 + l15) * 64;
      short8 vb0 = *(const short8*)(vr + c0);
      short8 vb1 = *(const short8*)(vr + c1);
      o[n] = __builtin_amdgcn_mfma_f32_16x16x32_bf16(vb0, pa0, o[n], 0, 0, 0);
      o[n] = __builtin_amdgcn_mfma_f32_16x16x32_bf16(vb1, pa1, o[n], 0, 0, 0);
    }
  }

  // ---- epilogue: per-lane 1/l, packed b64 stores
  int b = bh >> 4, h = bh & 15;
  float inv = 1.f / l_i;
  int s = qbase + wave * 16 + l15;
  size_t orow = (size_t)(b * 2048 + s) * 1024 + h * 64;
#pragma unroll
  for (int n = 0; n < 4; ++n) {
    uint2 ov;
    ov.x = pk2bf(o[n][0] * inv, o[n][1] * inv);
    ov.y = pk2bf(o[n][2] * inv, o[n][3] * inv);
    *(uint2*)(Oc + orow + n * 16 + quad * 4) = ov;
  }
}

// ---------------------------------------------------------------------------
extern "C" void kernel_launch(void* const* d_in, const int* in_sizes, int n_in,
                              void* d_out, int out_size, void* d_ws, size_t ws_size,
                              hipStream_t stream) {
  const float* x  = (const float*)d_in[0];
  const int* tokpos = (const int*)d_in[1];
  const float* Wq = (const float*)d_in[2];
  const float* Wk = (const float*)d_in[3];
  const float* Wv = (const float*)d_in[4];
  const float* Wo = (const float*)d_in[5];
  float* out = (float*)d_out;

  float* ws = (float*)d_ws;
  float* ctab = ws;
  float* stab = ctab + 65536;
  unsigned short* u = (unsigned short*)(stab + 65536);
  unsigned short* Qb  = u;
  unsigned short* Kb  = Qb + 4194304;
  unsigned short* Vb  = Kb + 4194304;   // transposed [bh][d][s]
  unsigned short* Oc  = Vb + 4194304;
  unsigned short* xb  = Oc + 4194304;
  unsigned short* Wqb = xb + 4194304;
  unsigned short* Wkb = Wqb + 1048576;
  unsigned short* Wvb = Wkb + 1048576;
  unsigned short* Wob = Wvb + 1048576;

  cvt_all<<<dim3(4096, 6), 256, 0, stream>>>(
      (const float4*)x, (const float4*)Wq, (const float4*)Wk,
      (const float4*)Wv, (const float4*)Wo,
      (ushort4*)xb, (ushort4*)Wqb, (ushort4*)Wkb, (ushort4*)Wvb, (ushort4*)Wob,
      tokpos, ctab, stab);

  qkv_mfma<<<dim3(32, 8, 3), 256, 0, stream>>>(
      xb, Wqb, Wkb, Wvb, ctab, stab, Qb, Kb, Vb);
  attn_flash<<<dim3(32, 32), 256, 0, stream>>>(Qb, Kb, Vb, Oc);
  oproj_mfma<<<dim3(64, 8), 256, 0, stream>>>(Oc, Wob, out);
}

// Round 2
// 186.349 us; speedup vs baseline: 1.0462x; 1.0462x over previous
//
#include <hip/hip_runtime.h>
#include <hip/hip_bf16.h>

// B=2, S=2048, D=1024, H=16, DK=64, THETA=10000
// Inputs fp32 (positions int32): x[2,2048,1024], token_positions[2048],
// Wq,Wk,Wv,Wo [1024,1024].  Output fp32 [2,2048,1024].
// proj: y[b,s,o] = sum_d x[b,s,d] * W[o,d]

typedef __attribute__((ext_vector_type(8))) short short8;   // 8 bf16 = 4 VGPRs
typedef __attribute__((ext_vector_type(4))) float floatx4;  // MFMA accumulator

static __device__ __forceinline__ unsigned short f2bf(float f) {
  __hip_bfloat16 h = __float2bfloat16(f);
  return *(unsigned short*)&h;
}

// pack 2 floats -> 2 bf16 in one u32 (half-up rounding + v_perm byte pick).
// low ushort = bf16(a), high ushort = bf16(b). Finite inputs only.
static __device__ __forceinline__ unsigned int pk2bf(float a, float b) {
  unsigned int ua = __float_as_uint(a) + 0x8000u;
  unsigned int ub = __float_as_uint(b) + 0x8000u;
  return __builtin_amdgcn_perm(ub, ua, 0x07060302u);
}

// raw v_exp_f32 (2^x), single VALU transcendental; s_nop covers the
// trans->VALU dependency wait state.
static __device__ __forceinline__ float fexp2(float x) {
  float r;
  asm("v_exp_f32 %0, %1\n\ts_nop 0" : "=v"(r) : "v"(x));
  return r;
}

// async global->LDS DMA, 16 B per lane; lds base must be wave-uniform,
// HW writes lane i at ldsbase + i*16.
static __device__ __forceinline__ void gl2lds16(const unsigned short* g,
                                                unsigned short* l) {
  __builtin_amdgcn_global_load_lds(
      (const __attribute__((address_space(1))) void*)g,
      (__attribute__((address_space(3))) void*)l, 16, 0, 0);
}

// ---------------------------------------------------------------------------
// fp32 -> bf16 conversion for all 5 tensors + RoPE table gen, one launch.
// blockIdx.y: 0=x 1=Wq 2=Wk 3=Wv 4=Wo 5=rope tables
// ---------------------------------------------------------------------------
__global__ __launch_bounds__(256) void cvt_all(
    const float4* __restrict__ x,  const float4* __restrict__ wq,
    const float4* __restrict__ wk, const float4* __restrict__ wv,
    const float4* __restrict__ wo,
    ushort4* __restrict__ xb,  ushort4* __restrict__ wqb,
    ushort4* __restrict__ wkb, ushort4* __restrict__ wvb,
    ushort4* __restrict__ wob,
    const int* __restrict__ tokpos,
    float* __restrict__ ctab, float* __restrict__ stab) {
  int t = blockIdx.y;
  int i = blockIdx.x * 256 + threadIdx.x;
  if (t == 5) {
    if (i < 65536) {     // 2048 positions x 32 pair-freqs
      int s = i >> 5, f = i & 31;
      float inv = expf(-9.210340371976184f * (float)(2 * f) / 64.0f);
      float ang = (float)tokpos[s] * inv;
      ctab[i] = cosf(ang);
      stab[i] = sinf(ang);
    }
    return;
  }
  const float4* s = (t == 0) ? x : (t == 1) ? wq : (t == 2) ? wk : (t == 3) ? wv : wo;
  ushort4* d = (t == 0) ? xb : (t == 1) ? wqb : (t == 2) ? wkb : (t == 3) ? wvb : wob;
  int n4 = (t == 0) ? 1048576 : 262144;
  if (i < n4) {
    float4 v = s[i];
    ushort4 o;
    o.x = f2bf(v.x); o.y = f2bf(v.y); o.z = f2bf(v.z); o.w = f2bf(v.w);
    d[i] = o;
  }
}

// ---------------------------------------------------------------------------
// 128x128-tile GEMM body, R11: depth-2 counted-vmcnt pipeline (T4 / AITER
// pattern).  R10's __syncthreads dbuf was null (== documented m99/m100):
// __syncthreads lowers to s_waitcnt vmcnt(0) which drains the just-issued
// prefetch at every barrier.  Now raw s_barrier + counted vmcnt:
//   compute(slot kt&1)
//   s_barrier                      (A) all waves done reading slot kt&1
//   issue L(kt+2) -> slot kt&1     8 DMA loads, stay in flight ~1.5 iters
//   s_waitcnt vmcnt(8)             waits ONLY for L(kt+1); L(kt+2) flying
//   s_barrier                      (B) slot kt&1^1 ready on all waves
// vmcnt ledger: outstanding after issue = 8 (L(kt+1)) + 8 (L(kt+2));
// vmcnt(8) retires the oldest 8 = L(kt+1).  Tail kt=14: vmcnt(0) drains
// L(15).  Race-safety: all ds_reads of a slot feed MFMAs before (A)
// (compiler lgkmcnt waits); "memory" clobber on the waitcnt asm pins next
// iter's LDS reads behind (B).  Staging/fragment addressing unchanged:
// global_load_lds width=16 into UNPADDED [128][64] tiles with XOR chunk
// swizzle (conflict-free, SQ_LDS_BANK_CONFLICT measured 0).
// ---------------------------------------------------------------------------
#define GEMM128_BODY(Aptr, Wptr, m0, n0)                                        \
  __shared__ __align__(16) unsigned short lA[2][128 * 64];                      \
  __shared__ __align__(16) unsigned short lB[2][128 * 64];                      \
  int tid = threadIdx.x;                                                        \
  int wave = tid >> 6, lane = tid & 63;                                         \
  int wm = wave >> 1, wn = wave & 1;                                            \
  int l15 = lane & 15, quad = lane >> 4;                                        \
  int srow = wave * 32 + (lane >> 3);  /* staging row (+p*8) */                 \
  int sch = lane & 7;                  /* staging 16B-chunk  */                 \
  int fsw = l15 & 7;                   /* fragment-read swizzle */              \
  floatx4 acc[4][4];                                                            \
  _Pragma("unroll") for (int m = 0; m < 4; ++m)                                 \
      _Pragma("unroll") for (int n = 0; n < 4; ++n)                             \
          acc[m][n] = (floatx4){0.f, 0.f, 0.f, 0.f};                            \
  /* prologue: L(0)->slot0 (8 loads), L(1)->slot1 (8 loads) */                  \
  _Pragma("unroll") for (int p = 0; p < 4; ++p) {                               \
    int r = srow + p * 8;                                                       \
    int g = sch ^ (r & 7);                                                      \
    gl2lds16(Aptr + (size_t)(m0 + r) * 1024 + g * 8,                            \
             lA[0] + (wave * 32 + p * 8) * 64);                                 \
    gl2lds16(Wptr + (size_t)(n0 + r) * 1024 + g * 8,                            \
             lB[0] + (wave * 32 + p * 8) * 64);                                 \
  }                                                                             \
  _Pragma("unroll") for (int p = 0; p < 4; ++p) {                               \
    int r = srow + p * 8;                                                       \
    int g = sch ^ (r & 7);                                                      \
    gl2lds16(Aptr + (size_t)(m0 + r) * 1024 + 64 + g * 8,                       \
             lA[1] + (wave * 32 + p * 8) * 64);                                 \
    gl2lds16(Wptr + (size_t)(n0 + r) * 1024 + 64 + g * 8,                       \
             lB[1] + (wave * 32 + p * 8) * 64);                                 \
  }                                                                             \
  asm volatile("s_waitcnt vmcnt(8)" ::: "memory"); /* L(0) done */              \
  __builtin_amdgcn_s_barrier();                                                 \
  for (int kt = 0; kt < 16; ++kt) {                                             \
    int cur = kt & 1;                                                           \
    _Pragma("unroll") for (int ks = 0; ks < 2; ++ks) {                          \
      short8 af[4], bf[4];                                                      \
      _Pragma("unroll") for (int m = 0; m < 4; ++m)                             \
          af[m] = *(const short8*)(lA[cur] + (wm * 64 + m * 16 + l15) * 64 +    \
                                   (((ks * 4 + quad) ^ fsw) * 8));              \
      _Pragma("unroll") for (int n = 0; n < 4; ++n)                             \
          bf[n] = *(const short8*)(lB[cur] + (wn * 64 + n * 16 + l15) * 64 +    \
                                   (((ks * 4 + quad) ^ fsw) * 8));              \
      _Pragma("unroll") for (int m = 0; m < 4; ++m)                             \
          _Pragma("unroll") for (int n = 0; n < 4; ++n)                         \
              acc[m][n] = __builtin_amdgcn_mfma_f32_16x16x32_bf16(              \
                  af[m], bf[n], acc[m][n], 0, 0, 0);                            \
    }                                                                           \
    if (kt == 15) break;                                                        \
    __builtin_amdgcn_s_barrier(); /* (A) */                                     \
    if (kt < 14) {                                                              \
      _Pragma("unroll") for (int p = 0; p < 4; ++p) {                           \
        int r = srow + p * 8;                                                   \
        int g = sch ^ (r & 7);                                                  \
        gl2lds16(Aptr + (size_t)(m0 + r) * 1024 + (kt + 2) * 64 + g * 8,        \
                 lA[cur] + (wave * 32 + p * 8) * 64);                           \
        gl2lds16(Wptr + (size_t)(n0 + r) * 1024 + (kt + 2) * 64 + g * 8,        \
                 lB[cur] + (wave * 32 + p * 8) * 64);                           \
      }                                                                         \
      asm volatile("s_waitcnt vmcnt(8)" ::: "memory"); /* L(kt+1) done */       \
    } else {                                                                    \
      asm volatile("s_waitcnt vmcnt(0)" ::: "memory"); /* drain L(15) */        \
    }                                                                           \
    __builtin_amdgcn_s_barrier(); /* (B) */                                     \
  }

// ---------------------------------------------------------------------------
// QKV projection, tiled MFMA GEMM + fused RoPE epilogue.
// Q pre-scaled by (1/sqrt(64))*log2(e) so attention uses raw v_exp_f32.
// Q,K bf16 [bh][s][64]; V transposed [bh][d][2048].
// ---------------------------------------------------------------------------
__global__ __launch_bounds__(256) void qkv_mfma(
    const unsigned short* __restrict__ X,
    const unsigned short* __restrict__ Wq,
    const unsigned short* __restrict__ Wk,
    const unsigned short* __restrict__ Wv,
    const float* __restrict__ ctab, const float* __restrict__ stab,
    unsigned short* __restrict__ Qo, unsigned short* __restrict__ Ko,
    unsigned short* __restrict__ Vo) {
  int mat = blockIdx.z;  // 0=q 1=k 2=v
  const unsigned short* W = (mat == 0) ? Wq : ((mat == 1) ? Wk : Wv);
  unsigned short* Out = (mat == 0) ? Qo : ((mat == 1) ? Ko : Vo);
  int m0 = blockIdx.x * 128, n0 = blockIdx.y * 128;

  GEMM128_BODY(X, W, m0, n0)

#pragma unroll
  for (int n = 0; n < 4; ++n) {
    int col = n0 + wn * 64 + n * 16 + l15;  // 0..1023
    int h = col >> 6;
    int d = col & 63;
    int pi = d >> 1;
    bool odd = (d & 1) != 0;
    size_t hb = (size_t)h * 2048 * 64;
#pragma unroll
    for (int m = 0; m < 4; ++m) {
      int row0 = m0 + wm * 64 + m * 16 + quad * 4;  // rows row0..row0+3
      int b = row0 >> 11;
      int s0 = row0 & 2047;
      size_t base = (size_t)b * 16 * 2048 * 64 + hb;
      if (mat == 2) {
        // V: packed b64 store along s (transposed layout [d][s])
        ushort4 pv;
        pv.x = f2bf(acc[m][n][0]);
        pv.y = f2bf(acc[m][n][1]);
        pv.z = f2bf(acc[m][n][2]);
        pv.w = f2bf(acc[m][n][3]);
        *(ushort4*)(Out + base + (size_t)d * 2048 + s0) = pv;
      } else {
#pragma unroll
        for (int i = 0; i < 4; ++i) {
          int s = s0 + i;
          float v = acc[m][n][i];
          float p = __shfl_xor(v, 1);
          float c = ctab[s * 32 + pi];
          float sn = stab[s * 32 + pi];
          float res = odd ? fmaf(p, sn, v * c) : fmaf(v, c, -p * sn);
          if (mat == 0) res *= 0.1803368801111204f;  // 0.125 * log2(e)
          Out[base + (size_t)s * 64 + d] = f2bf(res);
        }
      }
    }
  }
}

// ---------------------------------------------------------------------------
// Output projection: out = Oc @ Wo^T.  64x128 tiles -> 512 blocks (2/CU).
// Same depth-2 counted-vmcnt pipeline as GEMM128 (R11); 6 DMA loads/thread
// per tile -> vmcnt(6).  fp32 store.
// ---------------------------------------------------------------------------
__global__ __launch_bounds__(256) void oproj_mfma(
    const unsigned short* __restrict__ A, const unsigned short* __restrict__ Wo,
    float* __restrict__ Out) {
  __shared__ __align__(16) unsigned short lA[2][64 * 64];
  __shared__ __align__(16) unsigned short lB[2][128 * 64];
  int tid = threadIdx.x;
  int wave = tid >> 6, lane = tid & 63;
  int l15 = lane & 15, quad = lane >> 4;
  int rsub = lane >> 3, sch = lane & 7;
  int fsw = l15 & 7;
  int m0 = blockIdx.x * 64, n0 = blockIdx.y * 128;

  floatx4 acc[4][2];
#pragma unroll
  for (int m = 0; m < 4; ++m)
#pragma unroll
    for (int n = 0; n < 2; ++n) acc[m][n] = (floatx4){0.f, 0.f, 0.f, 0.f};

  // prologue: L(0)->slot0 (6 loads), L(1)->slot1 (6 loads)
#pragma unroll
  for (int kp = 0; kp < 2; ++kp) {
#pragma unroll
    for (int p = 0; p < 2; ++p) {
      int r = wave * 16 + p * 8 + rsub;
      int g = sch ^ (r & 7);
      gl2lds16(A + (size_t)(m0 + r) * 1024 + kp * 64 + g * 8,
               lA[kp] + (wave * 16 + p * 8) * 64);
    }
#pragma unroll
    for (int p = 0; p < 4; ++p) {
      int r = wave * 32 + p * 8 + rsub;
      int g = sch ^ (r & 7);
      gl2lds16(Wo + (size_t)(n0 + r) * 1024 + kp * 64 + g * 8,
               lB[kp] + (wave * 32 + p * 8) * 64);
    }
  }
  asm volatile("s_waitcnt vmcnt(6)" ::: "memory");  // L(0) done
  __builtin_amdgcn_s_barrier();

  for (int kt = 0; kt < 16; ++kt) {
    int cur = kt & 1;
#pragma unroll
    for (int ks = 0; ks < 2; ++ks) {
      int slot = ((ks * 4 + quad) ^ fsw) * 8;
      short8 af[4], bf[2];
#pragma unroll
      for (int m = 0; m < 4; ++m)
        af[m] = *(const short8*)(lA[cur] + (m * 16 + l15) * 64 + slot);
#pragma unroll
      for (int n = 0; n < 2; ++n)
        bf[n] = *(const short8*)(lB[cur] + (wave * 32 + n * 16 + l15) * 64 + slot);
#pragma unroll
      for (int m = 0; m < 4; ++m)
#pragma unroll
        for (int n = 0; n < 2; ++n)
          acc[m][n] = __builtin_amdgcn_mfma_f32_16x16x32_bf16(
              af[m], bf[n], acc[m][n], 0, 0, 0);
    }
    if (kt == 15) break;
    __builtin_amdgcn_s_barrier();  // (A)
    if (kt < 14) {
#pragma unroll
      for (int p = 0; p < 2; ++p) {
        int r = wave * 16 + p * 8 + rsub;
        int g = sch ^ (r & 7);
        gl2lds16(A + (size_t)(m0 + r) * 1024 + (kt + 2) * 64 + g * 8,
                 lA[cur] + (wave * 16 + p * 8) * 64);
      }
#pragma unroll
      for (int p = 0; p < 4; ++p) {
        int r = wave * 32 + p * 8 + rsub;
        int g = sch ^ (r & 7);
        gl2lds16(Wo + (size_t)(n0 + r) * 1024 + (kt + 2) * 64 + g * 8,
                 lB[cur] + (wave * 32 + p * 8) * 64);
      }
      asm volatile("s_waitcnt vmcnt(6)" ::: "memory");  // L(kt+1) done
    } else {
      asm volatile("s_waitcnt vmcnt(0)" ::: "memory");  // drain L(15)
    }
    __builtin_amdgcn_s_barrier();  // (B)
  }

#pragma unroll
  for (int m = 0; m < 4; ++m) {
#pragma unroll
    for (int n = 0; n < 2; ++n) {
      int col = n0 + wave * 32 + n * 16 + l15;
#pragma unroll
      for (int i = 0; i < 4; ++i) {
        int row = m0 + m * 16 + quad * 4 + i;
        Out[(size_t)row * 1024 + col] = acc[m][n][i];
      }
    }
  }
}

// ---------------------------------------------------------------------------
// Flash attention: R8 shape (256 thr / 4 waves / 16 q per wave, 16 waves/CU)
// + R9's VALU cuts (raw v_exp_f32, v_perm bf16 packing).
// Transposed-score form: per-lane q softmax (in-lane tree + 2 shfl_xor).
// K/V LDS: unpadded stride-64 with XOR chunk swizzle (conflict-free).
// Register-prefetch double buffering for K/V staging.
// Balance swizzle: co-resident blocks {id,id+256,id+512,id+768} get qtiles
// {x, 31-x, (15-x)&31, (16+x)&31} -> 66 tile-iters per CU for every x.
// ---------------------------------------------------------------------------
#define LPS 72  // lP row stride

__global__ __launch_bounds__(256) void attn_flash(
    const unsigned short* __restrict__ Q, const unsigned short* __restrict__ K,
    const unsigned short* __restrict__ Vt, unsigned short* __restrict__ Oc) {
  __shared__ __align__(16) unsigned short lK[64 * 64];   // [kj][d] swizzled
  __shared__ __align__(16) unsigned short lV[64 * 64];   // [d][kj] swizzled
  __shared__ unsigned short lP[4][16 * LPS];             // per-wave [q][kj]

  int tid = threadIdx.x;
  int wave = tid >> 6, lane = tid & 63;
  int l15 = lane & 15, quad = lane >> 4;

  int xb_ = blockIdx.x;          // 0..31
  int yb_ = blockIdx.y;          // 0..31
  int jb = yb_ >> 3, ib = yb_ & 7;
  int qtile;
  if (jb == 0)      qtile = xb_;
  else if (jb == 1) qtile = 31 - xb_;
  else if (jb == 2) qtile = (15 - xb_) & 31;
  else              qtile = (16 + xb_) & 31;
  int bh = ib * 4 + jb;

  size_t base = (size_t)bh * 2048 * 64;
  int qbase = qtile * 64;

  // Q rows as B-operand fragments (B[k=d][n=q]); q = wavebase + l15
  const unsigned short* qrow = Q + base + (size_t)(qbase + wave * 16 + l15) * 64;
  short8 qb0 = *(const short8*)(qrow + quad * 8);
  short8 qb1 = *(const short8*)(qrow + 32 + quad * 8);

  floatx4 o[4];          // O^T[d = n*16+quad*4+reg][q = l15]
  float m_i = -1e30f, l_i = 0.f;   // per-lane softmax state (q = l15)
#pragma unroll
  for (int n = 0; n < 4; ++n) o[n] = (floatx4){0.f, 0.f, 0.f, 0.f};

  // staging: thread covers rows r0,r1 (r1=r0+32, same &7), global chunk g
  int r0 = tid >> 3, g = tid & 7;
  int r1 = r0 + 32;
  int e0 = g * 8;                       // global element offset of chunk g
  int sl = (g ^ (r0 & 7)) * 8;          // swizzled LDS slot (element offset)
  int fsw = l15 & 7;                    // fragment-read swizzle
  int c0 = (quad ^ fsw) * 8;            // slot of global chunk quad
  int c1 = ((quad + 4) ^ fsw) * 8;      // slot of global chunk quad+4

  // prefetch kt=0
  const unsigned short* kp = K + base;
  const unsigned short* vp = Vt + base;
  short8 pk0 = *(const short8*)(kp + r0 * 64 + e0);
  short8 pk1 = *(const short8*)(kp + r1 * 64 + e0);
  short8 pv0 = *(const short8*)(vp + (size_t)r0 * 2048 + e0);
  short8 pv1 = *(const short8*)(vp + (size_t)r1 * 2048 + e0);

  for (int kt = 0; kt <= qtile; ++kt) {
    __syncthreads();   // all waves done reading lK/lV from previous iter
    *(short8*)(lK + r0 * 64 + sl) = pk0;
    *(short8*)(lK + r1 * 64 + sl) = pk1;
    *(short8*)(lV + r0 * 64 + sl) = pv0;
    *(short8*)(lV + r1 * 64 + sl) = pv1;
    __syncthreads();

    if (kt < qtile) {  // prefetch next tile; consumed at next iter's LDS write
      const unsigned short* kn = K + base + (size_t)(kt + 1) * 4096;
      const unsigned short* vn = Vt + base + (kt + 1) * 64;
      pk0 = *(const short8*)(kn + r0 * 64 + e0);
      pk1 = *(const short8*)(kn + r1 * 64 + e0);
      pv0 = *(const short8*)(vn + (size_t)r0 * 2048 + e0);
      pv1 = *(const short8*)(vn + (size_t)r1 * 2048 + e0);
    }

    // ---- S^T = K·Q^T : sc[sub][i] is score for kpos = sub*16+quad*4+i, q=l15
    float sc[4][4];
#pragma unroll
    for (int sub = 0; sub < 4; ++sub) {
      const unsigned short* kr = lK + (sub * 16 + l15) * 64;
      short8 a0 = *(const short8*)(kr + c0);
      short8 a1 = *(const short8*)(kr + c1);
      floatx4 s = {0.f, 0.f, 0.f, 0.f};
      s = __builtin_amdgcn_mfma_f32_16x16x32_bf16(a0, qb0, s, 0, 0, 0);
      s = __builtin_amdgcn_mfma_f32_16x16x32_bf16(a1, qb1, s, 0, 0, 0);
#pragma unroll
      for (int i = 0; i < 4; ++i) sc[sub][i] = s[i];
    }

    // ---- causal mask (diagonal tile only): k-within > q-within
    if (kt == qtile) {
      int qin = wave * 16 + l15;
#pragma unroll
      for (int sub = 0; sub < 4; ++sub)
#pragma unroll
        for (int i = 0; i < 4; ++i)
          if (sub * 16 + quad * 4 + i > qin) sc[sub][i] = -1e30f;
    }

    // ---- online softmax (log2 domain): in-lane tree + 2 cross-quad shuffles
    float mb = sc[0][0];
#pragma unroll
    for (int sub = 0; sub < 4; ++sub)
#pragma unroll
      for (int i = 0; i < 4; ++i) mb = fmaxf(mb, sc[sub][i]);
    mb = fmaxf(mb, __shfl_xor(mb, 16));
    mb = fmaxf(mb, __shfl_xor(mb, 32));

    float mn = fmaxf(m_i, mb);
    float al = fexp2(m_i - mn);
    m_i = mn;
    float rs = 0.f;
#pragma unroll
    for (int sub = 0; sub < 4; ++sub)
#pragma unroll
      for (int i = 0; i < 4; ++i) {
        float p = fexp2(sc[sub][i] - mn);
        sc[sub][i] = p;
        rs += p;
      }
    rs += __shfl_xor(rs, 16);
    rs += __shfl_xor(rs, 32);
    l_i = l_i * al + rs;

    // per-lane rescale of O^T columns (q = l15 matches softmax state)
#pragma unroll
    for (int n = 0; n < 4; ++n) {
      o[n][0] *= al; o[n][1] *= al; o[n][2] *= al; o[n][3] *= al;
    }

    // ---- P^T -> lP rows [q][k], packed pairs via v_perm
    unsigned short* pw = lP[wave] + l15 * LPS;
#pragma unroll
    for (int sub = 0; sub < 4; ++sub) {
      uint2 w;
      w.x = pk2bf(sc[sub][0], sc[sub][1]);
      w.y = pk2bf(sc[sub][2], sc[sub][3]);
      *(uint2*)(pw + sub * 16 + quad * 4) = w;
    }

    const unsigned short* pr = lP[wave] + l15 * LPS + quad * 8;
    short8 pa0 = *(const short8*)(pr);
    short8 pa1 = *(const short8*)(pr + 32);

    // ---- O^T += V^T·P^T : A = lV rows (d), B = lP rows (q)
#pragma unroll
    for (int n = 0; n < 4; ++n) {
      const unsigned short* vr = lV + (n * 16 + l15) * 64;
      short8 vb0 = *(const short8*)(vr + c0);
      short8 vb1 = *(const short8*)(vr + c1);
      o[n] = __builtin_amdgcn_mfma_f32_16x16x32_bf16(vb0, pa0, o[n], 0, 0, 0);
      o[n] = __builtin_amdgcn_mfma_f32_16x16x32_bf16(vb1, pa1, o[n], 0, 0, 0);
    }
  }

  // ---- epilogue: per-lane 1/l, packed b64 stores
  int b = bh >> 4, h = bh & 15;
  float inv = 1.f / l_i;
  int s = qbase + wave * 16 + l15;
  size_t orow = (size_t)(b * 2048 + s) * 1024 + h * 64;
#pragma unroll
  for (int n = 0; n < 4; ++n) {
    uint2 ov;
    ov.x = pk2bf(o[n][0] * inv, o[n][1] * inv);
    ov.y = pk2bf(o[n][2] * inv, o[n][3] * inv);
    *(uint2*)(Oc + orow + n * 16 + quad * 4) = ov;
  }
}

// ---------------------------------------------------------------------------
extern "C" void kernel_launch(void* const* d_in, const int* in_sizes, int n_in,
                              void* d_out, int out_size, void* d_ws, size_t ws_size,
                              hipStream_t stream) {
  const float* x  = (const float*)d_in[0];
  const int* tokpos = (const int*)d_in[1];
  const float* Wq = (const float*)d_in[2];
  const float* Wk = (const float*)d_in[3];
  const float* Wv = (const float*)d_in[4];
  const float* Wo = (const float*)d_in[5];
  float* out = (float*)d_out;

  float* ws = (float*)d_ws;
  float* ctab = ws;
  float* stab = ctab + 65536;
  unsigned short* u = (unsigned short*)(stab + 65536);
  unsigned short* Qb  = u;
  unsigned short* Kb  = Qb + 4194304;
  unsigned short* Vb  = Kb + 4194304;   // transposed [bh][d][s]
  unsigned short* Oc  = Vb + 4194304;
  unsigned short* xb  = Oc + 4194304;
  unsigned short* Wqb = xb + 4194304;
  unsigned short* Wkb = Wqb + 1048576;
  unsigned short* Wvb = Wkb + 1048576;
  unsigned short* Wob = Wvb + 1048576;

  cvt_all<<<dim3(4096, 6), 256, 0, stream>>>(
      (const float4*)x, (const float4*)Wq, (const float4*)Wk,
      (const float4*)Wv, (const float4*)Wo,
      (ushort4*)xb, (ushort4*)Wqb, (ushort4*)Wkb, (ushort4*)Wvb, (ushort4*)Wob,
      tokpos, ctab, stab);

  qkv_mfma<<<dim3(32, 8, 3), 256, 0, stream>>>(
      xb, Wqb, Wkb, Wvb, ctab, stab, Qb, Kb, Vb);
  attn_flash<<<dim3(32, 32), 256, 0, stream>>>(Qb, Kb, Vb, Oc);
  oproj_mfma<<<dim3(64, 8), 256, 0, stream>>>(Oc, Wob, out);
}

// Round 3
// 179.684 us; speedup vs baseline: 1.0850x; 1.0371x over previous
//
#include <hip/hip_runtime.h>
#include <hip/hip_bf16.h>

// B=2, S=2048, D=1024, H=16, DK=64, THETA=10000
// Inputs fp32 (positions int32): x[2,2048,1024], token_positions[2048],
// Wq,Wk,Wv,Wo [1024,1024].  Output fp32 [2,2048,1024].
// proj: y[b,s,o] = sum_d x[b,s,d] * W[o,d]

typedef __attribute__((ext_vector_type(8))) short short8;   // 8 bf16 = 4 VGPRs
typedef __attribute__((ext_vector_type(4))) float floatx4;  // MFMA accumulator

static __device__ __forceinline__ unsigned short f2bf(float f) {
  __hip_bfloat16 h = __float2bfloat16(f);
  return *(unsigned short*)&h;
}

// pack 2 floats -> 2 bf16 in one u32 (half-up rounding + v_perm byte pick).
// low ushort = bf16(a), high ushort = bf16(b). Finite inputs only.
static __device__ __forceinline__ unsigned int pk2bf(float a, float b) {
  unsigned int ua = __float_as_uint(a) + 0x8000u;
  unsigned int ub = __float_as_uint(b) + 0x8000u;
  return __builtin_amdgcn_perm(ub, ua, 0x07060302u);
}

// raw v_exp_f32 (2^x), single VALU transcendental; s_nop covers the
// trans->VALU dependency wait state.
static __device__ __forceinline__ float fexp2(float x) {
  float r;
  asm("v_exp_f32 %0, %1\n\ts_nop 0" : "=v"(r) : "v"(x));
  return r;
}

// async global->LDS DMA, 16 B per lane; lds base must be wave-uniform,
// HW writes lane i at ldsbase + i*16.
static __device__ __forceinline__ void gl2lds16(const unsigned short* g,
                                                unsigned short* l) {
  __builtin_amdgcn_global_load_lds(
      (const __attribute__((address_space(1))) void*)g,
      (__attribute__((address_space(3))) void*)l, 16, 0, 0);
}

// ---------------------------------------------------------------------------
// fp32 -> bf16 conversion for all 5 tensors + RoPE table gen, one launch.
// blockIdx.y: 0=x 1=Wq 2=Wk 3=Wv 4=Wo 5=rope tables
// ---------------------------------------------------------------------------
__global__ __launch_bounds__(256) void cvt_all(
    const float4* __restrict__ x,  const float4* __restrict__ wq,
    const float4* __restrict__ wk, const float4* __restrict__ wv,
    const float4* __restrict__ wo,
    ushort4* __restrict__ xb,  ushort4* __restrict__ wqb,
    ushort4* __restrict__ wkb, ushort4* __restrict__ wvb,
    ushort4* __restrict__ wob,
    const int* __restrict__ tokpos,
    float* __restrict__ ctab, float* __restrict__ stab) {
  int t = blockIdx.y;
  int i = blockIdx.x * 256 + threadIdx.x;
  if (t == 5) {
    if (i < 65536) {     // 2048 positions x 32 pair-freqs
      int s = i >> 5, f = i & 31;
      float inv = expf(-9.210340371976184f * (float)(2 * f) / 64.0f);
      float ang = (float)tokpos[s] * inv;
      ctab[i] = cosf(ang);
      stab[i] = sinf(ang);
    }
    return;
  }
  const float4* s = (t == 0) ? x : (t == 1) ? wq : (t == 2) ? wk : (t == 3) ? wv : wo;
  ushort4* d = (t == 0) ? xb : (t == 1) ? wqb : (t == 2) ? wkb : (t == 3) ? wvb : wob;
  int n4 = (t == 0) ? 1048576 : 262144;
  if (i < n4) {
    float4 v = s[i];
    ushort4 o;
    o.x = f2bf(v.x); o.y = f2bf(v.y); o.z = f2bf(v.z); o.w = f2bf(v.w);
    d[i] = o;
  }
}

// ---------------------------------------------------------------------------
// 128x128-tile GEMM body, R11: depth-2 counted-vmcnt pipeline (T4 / AITER
// pattern).  Raw s_barrier + counted vmcnt:
//   compute(slot kt&1)
//   s_barrier                      (A) all waves done reading slot kt&1
//   issue L(kt+2) -> slot kt&1     8 DMA loads, stay in flight ~1.5 iters
//   s_waitcnt vmcnt(8)             waits ONLY for L(kt+1); L(kt+2) flying
//   s_barrier                      (B) slot kt&1^1 ready on all waves
// vmcnt ledger: outstanding after issue = 8 (L(kt+1)) + 8 (L(kt+2));
// vmcnt(8) retires the oldest 8 = L(kt+1).  Tail kt=14: vmcnt(0) drains
// L(15).  Race-safety: all ds_reads of a slot feed MFMAs before (A)
// (compiler lgkmcnt waits); "memory" clobber on the waitcnt asm pins next
// iter's LDS reads behind (B).  Staging/fragment addressing unchanged:
// global_load_lds width=16 into UNPADDED [128][64] tiles with XOR chunk
// swizzle (conflict-free, SQ_LDS_BANK_CONFLICT measured 0).
// Measured R2: qkv dropped out of top-5 (was 52-55us all slots).
// ---------------------------------------------------------------------------
#define GEMM128_BODY(Aptr, Wptr, m0, n0)                                        \
  __shared__ __align__(16) unsigned short lA[2][128 * 64];                      \
  __shared__ __align__(16) unsigned short lB[2][128 * 64];                      \
  int tid = threadIdx.x;                                                        \
  int wave = tid >> 6, lane = tid & 63;                                         \
  int wm = wave >> 1, wn = wave & 1;                                            \
  int l15 = lane & 15, quad = lane >> 4;                                        \
  int srow = wave * 32 + (lane >> 3);  /* staging row (+p*8) */                 \
  int sch = lane & 7;                  /* staging 16B-chunk  */                 \
  int fsw = l15 & 7;                   /* fragment-read swizzle */              \
  floatx4 acc[4][4];                                                            \
  _Pragma("unroll") for (int m = 0; m < 4; ++m)                                 \
      _Pragma("unroll") for (int n = 0; n < 4; ++n)                             \
          acc[m][n] = (floatx4){0.f, 0.f, 0.f, 0.f};                            \
  /* prologue: L(0)->slot0 (8 loads), L(1)->slot1 (8 loads) */                  \
  _Pragma("unroll") for (int p = 0; p < 4; ++p) {                               \
    int r = srow + p * 8;                                                       \
    int g = sch ^ (r & 7);                                                      \
    gl2lds16(Aptr + (size_t)(m0 + r) * 1024 + g * 8,                            \
             lA[0] + (wave * 32 + p * 8) * 64);                                 \
    gl2lds16(Wptr + (size_t)(n0 + r) * 1024 + g * 8,                            \
             lB[0] + (wave * 32 + p * 8) * 64);                                 \
  }                                                                             \
  _Pragma("unroll") for (int p = 0; p < 4; ++p) {                               \
    int r = srow + p * 8;                                                       \
    int g = sch ^ (r & 7);                                                      \
    gl2lds16(Aptr + (size_t)(m0 + r) * 1024 + 64 + g * 8,                       \
             lA[1] + (wave * 32 + p * 8) * 64);                                 \
    gl2lds16(Wptr + (size_t)(n0 + r) * 1024 + 64 + g * 8,                       \
             lB[1] + (wave * 32 + p * 8) * 64);                                 \
  }                                                                             \
  asm volatile("s_waitcnt vmcnt(8)" ::: "memory"); /* L(0) done */              \
  __builtin_amdgcn_s_barrier();                                                 \
  for (int kt = 0; kt < 16; ++kt) {                                             \
    int cur = kt & 1;                                                           \
    _Pragma("unroll") for (int ks = 0; ks < 2; ++ks) {                          \
      short8 af[4], bf[4];                                                      \
      _Pragma("unroll") for (int m = 0; m < 4; ++m)                             \
          af[m] = *(const short8*)(lA[cur] + (wm * 64 + m * 16 + l15) * 64 +    \
                                   (((ks * 4 + quad) ^ fsw) * 8));              \
      _Pragma("unroll") for (int n = 0; n < 4; ++n)                             \
          bf[n] = *(const short8*)(lB[cur] + (wn * 64 + n * 16 + l15) * 64 +    \
                                   (((ks * 4 + quad) ^ fsw) * 8));              \
      _Pragma("unroll") for (int m = 0; m < 4; ++m)                             \
          _Pragma("unroll") for (int n = 0; n < 4; ++n)                         \
              acc[m][n] = __builtin_amdgcn_mfma_f32_16x16x32_bf16(              \
                  af[m], bf[n], acc[m][n], 0, 0, 0);                            \
    }                                                                           \
    if (kt == 15) break;                                                        \
    __builtin_amdgcn_s_barrier(); /* (A) */                                     \
    if (kt < 14) {                                                              \
      _Pragma("unroll") for (int p = 0; p < 4; ++p) {                           \
        int r = srow + p * 8;                                                   \
        int g = sch ^ (r & 7);                                                  \
        gl2lds16(Aptr + (size_t)(m0 + r) * 1024 + (kt + 2) * 64 + g * 8,        \
                 lA[cur] + (wave * 32 + p * 8) * 64);                           \
        gl2lds16(Wptr + (size_t)(n0 + r) * 1024 + (kt + 2) * 64 + g * 8,        \
                 lB[cur] + (wave * 32 + p * 8) * 64);                           \
      }                                                                         \
      asm volatile("s_waitcnt vmcnt(8)" ::: "memory"); /* L(kt+1) done */       \
    } else {                                                                    \
      asm volatile("s_waitcnt vmcnt(0)" ::: "memory"); /* drain L(15) */        \
    }                                                                           \
    __builtin_amdgcn_s_barrier(); /* (B) */                                     \
  }

// ---------------------------------------------------------------------------
// QKV projection, tiled MFMA GEMM + fused RoPE epilogue.
// Q pre-scaled by (1/sqrt(64))*log2(e) so attention uses raw v_exp_f32.
// Q,K bf16 [bh][s][64]; V transposed [bh][d][2048].
// ---------------------------------------------------------------------------
__global__ __launch_bounds__(256) void qkv_mfma(
    const unsigned short* __restrict__ X,
    const unsigned short* __restrict__ Wq,
    const unsigned short* __restrict__ Wk,
    const unsigned short* __restrict__ Wv,
    const float* __restrict__ ctab, const float* __restrict__ stab,
    unsigned short* __restrict__ Qo, unsigned short* __restrict__ Ko,
    unsigned short* __restrict__ Vo) {
  int mat = blockIdx.z;  // 0=q 1=k 2=v
  const unsigned short* W = (mat == 0) ? Wq : ((mat == 1) ? Wk : Wv);
  unsigned short* Out = (mat == 0) ? Qo : ((mat == 1) ? Ko : Vo);
  int m0 = blockIdx.x * 128, n0 = blockIdx.y * 128;

  GEMM128_BODY(X, W, m0, n0)

#pragma unroll
  for (int n = 0; n < 4; ++n) {
    int col = n0 + wn * 64 + n * 16 + l15;  // 0..1023
    int h = col >> 6;
    int d = col & 63;
    int pi = d >> 1;
    bool odd = (d & 1) != 0;
    size_t hb = (size_t)h * 2048 * 64;
#pragma unroll
    for (int m = 0; m < 4; ++m) {
      int row0 = m0 + wm * 64 + m * 16 + quad * 4;  // rows row0..row0+3
      int b = row0 >> 11;
      int s0 = row0 & 2047;
      size_t base = (size_t)b * 16 * 2048 * 64 + hb;
      if (mat == 2) {
        // V: packed b64 store along s (transposed layout [d][s])
        ushort4 pv;
        pv.x = f2bf(acc[m][n][0]);
        pv.y = f2bf(acc[m][n][1]);
        pv.z = f2bf(acc[m][n][2]);
        pv.w = f2bf(acc[m][n][3]);
        *(ushort4*)(Out + base + (size_t)d * 2048 + s0) = pv;
      } else {
#pragma unroll
        for (int i = 0; i < 4; ++i) {
          int s = s0 + i;
          float v = acc[m][n][i];
          float p = __shfl_xor(v, 1);
          float c = ctab[s * 32 + pi];
          float sn = stab[s * 32 + pi];
          float res = odd ? fmaf(p, sn, v * c) : fmaf(v, c, -p * sn);
          if (mat == 0) res *= 0.1803368801111204f;  // 0.125 * log2(e)
          Out[base + (size_t)s * 64 + d] = f2bf(res);
        }
      }
    }
  }
}

// ---------------------------------------------------------------------------
// Output projection: out = Oc @ Wo^T.  64x128 tiles -> 512 blocks (2/CU).
// Same depth-2 counted-vmcnt pipeline as GEMM128 (R11); 6 DMA loads/thread
// per tile -> vmcnt(6).  fp32 store.
// ---------------------------------------------------------------------------
__global__ __launch_bounds__(256) void oproj_mfma(
    const unsigned short* __restrict__ A, const unsigned short* __restrict__ Wo,
    float* __restrict__ Out) {
  __shared__ __align__(16) unsigned short lA[2][64 * 64];
  __shared__ __align__(16) unsigned short lB[2][128 * 64];
  int tid = threadIdx.x;
  int wave = tid >> 6, lane = tid & 63;
  int l15 = lane & 15, quad = lane >> 4;
  int rsub = lane >> 3, sch = lane & 7;
  int fsw = l15 & 7;
  int m0 = blockIdx.x * 64, n0 = blockIdx.y * 128;

  floatx4 acc[4][2];
#pragma unroll
  for (int m = 0; m < 4; ++m)
#pragma unroll
    for (int n = 0; n < 2; ++n) acc[m][n] = (floatx4){0.f, 0.f, 0.f, 0.f};

  // prologue: L(0)->slot0 (6 loads), L(1)->slot1 (6 loads)
#pragma unroll
  for (int kp = 0; kp < 2; ++kp) {
#pragma unroll
    for (int p = 0; p < 2; ++p) {
      int r = wave * 16 + p * 8 + rsub;
      int g = sch ^ (r & 7);
      gl2lds16(A + (size_t)(m0 + r) * 1024 + kp * 64 + g * 8,
               lA[kp] + (wave * 16 + p * 8) * 64);
    }
#pragma unroll
    for (int p = 0; p < 4; ++p) {
      int r = wave * 32 + p * 8 + rsub;
      int g = sch ^ (r & 7);
      gl2lds16(Wo + (size_t)(n0 + r) * 1024 + kp * 64 + g * 8,
               lB[kp] + (wave * 32 + p * 8) * 64);
    }
  }
  asm volatile("s_waitcnt vmcnt(6)" ::: "memory");  // L(0) done
  __builtin_amdgcn_s_barrier();

  for (int kt = 0; kt < 16; ++kt) {
    int cur = kt & 1;
#pragma unroll
    for (int ks = 0; ks < 2; ++ks) {
      int slot = ((ks * 4 + quad) ^ fsw) * 8;
      short8 af[4], bf[2];
#pragma unroll
      for (int m = 0; m < 4; ++m)
        af[m] = *(const short8*)(lA[cur] + (m * 16 + l15) * 64 + slot);
#pragma unroll
      for (int n = 0; n < 2; ++n)
        bf[n] = *(const short8*)(lB[cur] + (wave * 32 + n * 16 + l15) * 64 + slot);
#pragma unroll
      for (int m = 0; m < 4; ++m)
#pragma unroll
        for (int n = 0; n < 2; ++n)
          acc[m][n] = __builtin_amdgcn_mfma_f32_16x16x32_bf16(
              af[m], bf[n], acc[m][n], 0, 0, 0);
    }
    if (kt == 15) break;
    __builtin_amdgcn_s_barrier();  // (A)
    if (kt < 14) {
#pragma unroll
      for (int p = 0; p < 2; ++p) {
        int r = wave * 16 + p * 8 + rsub;
        int g = sch ^ (r & 7);
        gl2lds16(A + (size_t)(m0 + r) * 1024 + (kt + 2) * 64 + g * 8,
                 lA[cur] + (wave * 16 + p * 8) * 64);
      }
#pragma unroll
      for (int p = 0; p < 4; ++p) {
        int r = wave * 32 + p * 8 + rsub;
        int g = sch ^ (r & 7);
        gl2lds16(Wo + (size_t)(n0 + r) * 1024 + (kt + 2) * 64 + g * 8,
                 lB[cur] + (wave * 32 + p * 8) * 64);
      }
      asm volatile("s_waitcnt vmcnt(6)" ::: "memory");  // L(kt+1) done
    } else {
      asm volatile("s_waitcnt vmcnt(0)" ::: "memory");  // drain L(15)
    }
    __builtin_amdgcn_s_barrier();  // (B)
  }

#pragma unroll
  for (int m = 0; m < 4; ++m) {
#pragma unroll
    for (int n = 0; n < 2; ++n) {
      int col = n0 + wave * 32 + n * 16 + l15;
#pragma unroll
      for (int i = 0; i < 4; ++i) {
        int row = m0 + m * 16 + quad * 4 + i;
        Out[(size_t)row * 1024 + col] = acc[m][n][i];
      }
    }
  }
}

// ---------------------------------------------------------------------------
// Flash attention R12: dual-stream uniform blocks.
// R2 diagnosis: latency-bound, occupancy 22% (block lifetimes 1..32 iters ->
// residency decays from 16 waves/CU to 4 as short blocks finish; avg ~1.75
// waves/SIMD; per-iter slot ~1855cy vs ~600cy issue work; all pipes <15%).
// Fix: one block processes the PAIR of q-tiles (x, 31-x).  Both streams
// consume the SAME staged kv-tile kt each iter (A active kt<=x, B always),
// so every block is exactly 33 work-units (uniform -> sustained residency),
// staging+barriers are shared (per-unit cost halves), and each wave carries
// TWO independent QK->softmax->PV chains whose latencies mutually hide.
// Grid 512 blocks (2/CU sustained).  XCD-clustered id: id%8 = bh>>2 so each
// bh's 512KB K/V stays in one XCD L2 (4bh x 512KB = 2MB < 4MB) -- R2 FETCH
// was 62.6MB vs ~24MB ideal = L2 thrash.
// Per-stream inner math identical to R8/R9 verified code (factored into
// forceinline helpers).  lP: per-(wave,stream) sub-buffers, no barrier needed
// (same-wave DS ops are ordered).
// ---------------------------------------------------------------------------
#define LPS 72  // lP row stride

static __device__ __forceinline__ void qk_step(
    const unsigned short* lK, int l15, int c0, int c1,
    short8 q0, short8 q1, floatx4 (&sc)[4]) {
#pragma unroll
  for (int sub = 0; sub < 4; ++sub) {
    const unsigned short* kr = lK + (sub * 16 + l15) * 64;
    short8 a0 = *(const short8*)(kr + c0);
    short8 a1 = *(const short8*)(kr + c1);
    floatx4 s = {0.f, 0.f, 0.f, 0.f};
    s = __builtin_amdgcn_mfma_f32_16x16x32_bf16(a0, q0, s, 0, 0, 0);
    s = __builtin_amdgcn_mfma_f32_16x16x32_bf16(a1, q1, s, 0, 0, 0);
    sc[sub] = s;
  }
}

static __device__ __forceinline__ void sm_step(
    floatx4 (&sc)[4], float& m_i, float& l_i, floatx4 (&o)[4],
    bool diag, int qin, int quad) {
  if (diag) {  // causal mask on diagonal tile: k-within > q-within
#pragma unroll
    for (int sub = 0; sub < 4; ++sub)
#pragma unroll
      for (int i = 0; i < 4; ++i)
        if (sub * 16 + quad * 4 + i > qin) sc[sub][i] = -1e30f;
  }
  float mb = sc[0][0];
#pragma unroll
  for (int sub = 0; sub < 4; ++sub)
#pragma unroll
    for (int i = 0; i < 4; ++i) mb = fmaxf(mb, sc[sub][i]);
  mb = fmaxf(mb, __shfl_xor(mb, 16));
  mb = fmaxf(mb, __shfl_xor(mb, 32));

  float mn = fmaxf(m_i, mb);
  float al = fexp2(m_i - mn);
  m_i = mn;
  float rs = 0.f;
#pragma unroll
  for (int sub = 0; sub < 4; ++sub)
#pragma unroll
    for (int i = 0; i < 4; ++i) {
      float p = fexp2(sc[sub][i] - mn);
      sc[sub][i] = p;
      rs += p;
    }
  rs += __shfl_xor(rs, 16);
  rs += __shfl_xor(rs, 32);
  l_i = l_i * al + rs;
#pragma unroll
  for (int n = 0; n < 4; ++n) {
    o[n][0] *= al; o[n][1] *= al; o[n][2] *= al; o[n][3] *= al;
  }
}

static __device__ __forceinline__ void pv_step(
    const floatx4 (&sc)[4], floatx4 (&o)[4], unsigned short* lPw,
    const unsigned short* lV, int l15, int quad, int c0, int c1) {
  unsigned short* pw = lPw + l15 * LPS;
#pragma unroll
  for (int sub = 0; sub < 4; ++sub) {
    uint2 w;
    w.x = pk2bf(sc[sub][0], sc[sub][1]);
    w.y = pk2bf(sc[sub][2], sc[sub][3]);
    *(uint2*)(pw + sub * 16 + quad * 4) = w;
  }
  const unsigned short* pr = lPw + l15 * LPS + quad * 8;
  short8 pa0 = *(const short8*)(pr);
  short8 pa1 = *(const short8*)(pr + 32);
#pragma unroll
  for (int n = 0; n < 4; ++n) {
    const unsigned short* vr = lV + (n * 16 + l15) * 64;
    short8 vb0 = *(const short8*)(vr + c0);
    short8 vb1 = *(const short8*)(vr + c1);
    o[n] = __builtin_amdgcn_mfma_f32_16x16x32_bf16(vb0, pa0, o[n], 0, 0, 0);
    o[n] = __builtin_amdgcn_mfma_f32_16x16x32_bf16(vb1, pa1, o[n], 0, 0, 0);
  }
}

__global__ __launch_bounds__(256, 2) void attn_flash(
    const unsigned short* __restrict__ Q, const unsigned short* __restrict__ K,
    const unsigned short* __restrict__ Vt, unsigned short* __restrict__ Oc) {
  __shared__ __align__(16) unsigned short lK[64 * 64];   // [kj][d] swizzled
  __shared__ __align__(16) unsigned short lV[64 * 64];   // [d][kj] swizzled
  __shared__ unsigned short lP[8][16 * LPS];             // [wave*2+stream]

  int tid = threadIdx.x;
  int wave = tid >> 6, lane = tid & 63;
  int l15 = lane & 15, quad = lane >> 4;

  // XCD-clustered decode: id%8 = bh>>2 (4 bh per XCD -> K/V L2-resident)
  int id = blockIdx.x;              // 0..511
  int rest = id >> 3;               // 0..63
  int pair = rest >> 2;             // 0..15
  int bh = (id & 7) * 4 + (rest & 3);
  int tA = pair;                    // small tile
  int tB = 31 - pair;               // big tile (always active)
  int NT = tB + 1;                  // kv tiles this block

  size_t base = (size_t)bh * 2048 * 64;

  // Q fragments (B-operand, loop-invariant) for both streams
  const unsigned short* qrowA = Q + base + (size_t)(tA * 64 + wave * 16 + l15) * 64;
  const unsigned short* qrowB = Q + base + (size_t)(tB * 64 + wave * 16 + l15) * 64;
  short8 qA0 = *(const short8*)(qrowA + quad * 8);
  short8 qA1 = *(const short8*)(qrowA + 32 + quad * 8);
  short8 qB0 = *(const short8*)(qrowB + quad * 8);
  short8 qB1 = *(const short8*)(qrowB + 32 + quad * 8);

  floatx4 oA[4], oB[4];
  float mA_i = -1e30f, lA_i = 0.f, mB_i = -1e30f, lB_i = 0.f;
#pragma unroll
  for (int n = 0; n < 4; ++n) {
    oA[n] = (floatx4){0.f, 0.f, 0.f, 0.f};
    oB[n] = (floatx4){0.f, 0.f, 0.f, 0.f};
  }

  // staging: thread covers rows r0,r1 (r1=r0+32, same &7), global chunk g
  int r0 = tid >> 3, g = tid & 7;
  int r1 = r0 + 32;
  int e0 = g * 8;                       // global element offset of chunk g
  int sl = (g ^ (r0 & 7)) * 8;          // swizzled LDS slot (element offset)
  int fsw = l15 & 7;                    // fragment-read swizzle
  int c0 = (quad ^ fsw) * 8;            // slot of global chunk quad
  int c1 = ((quad + 4) ^ fsw) * 8;      // slot of global chunk quad+4

  // prefetch kt=0
  const unsigned short* kp = K + base;
  const unsigned short* vp = Vt + base;
  short8 pk0 = *(const short8*)(kp + r0 * 64 + e0);
  short8 pk1 = *(const short8*)(kp + r1 * 64 + e0);
  short8 pv0 = *(const short8*)(vp + (size_t)r0 * 2048 + e0);
  short8 pv1 = *(const short8*)(vp + (size_t)r1 * 2048 + e0);

  int qin = wave * 16 + l15;  // q-row within tile (for diagonal mask)

  for (int kt = 0; kt < NT; ++kt) {
    bool aAct = (kt <= tA);

    __syncthreads();   // all waves done reading lK/lV from previous iter
    *(short8*)(lK + r0 * 64 + sl) = pk0;
    *(short8*)(lK + r1 * 64 + sl) = pk1;
    *(short8*)(lV + r0 * 64 + sl) = pv0;
    *(short8*)(lV + r1 * 64 + sl) = pv1;
    __syncthreads();

    if (kt + 1 < NT) {  // prefetch next tile; consumed at next iter's write
      const unsigned short* kn = K + base + (size_t)(kt + 1) * 4096;
      const unsigned short* vn = Vt + base + (kt + 1) * 64;
      pk0 = *(const short8*)(kn + r0 * 64 + e0);
      pk1 = *(const short8*)(kn + r1 * 64 + e0);
      pv0 = *(const short8*)(vn + (size_t)r0 * 2048 + e0);
      pv1 = *(const short8*)(vn + (size_t)r1 * 2048 + e0);
    }

    // ---- dual-stream compute: B always, A while kt <= tA.  Phases ordered
    // so stream A's MFMAs queue while stream B's softmax VALU chain runs.
    floatx4 scB[4], scA[4];
    qk_step(lK, l15, c0, c1, qB0, qB1, scB);
    if (aAct) qk_step(lK, l15, c0, c1, qA0, qA1, scA);

    sm_step(scB, mB_i, lB_i, oB, kt == NT - 1, qin, quad);
    if (aAct) sm_step(scA, mA_i, lA_i, oA, kt == tA, qin, quad);

    pv_step(scB, oB, lP[wave * 2], lV, l15, quad, c0, c1);
    if (aAct) pv_step(scA, oA, lP[wave * 2 + 1], lV, l15, quad, c0, c1);
  }

  // ---- epilogue: per-lane 1/l, packed b64 stores for both streams
  int b = bh >> 4, h = bh & 15;
  {
    float inv = 1.f / lB_i;
    int s = tB * 64 + wave * 16 + l15;
    size_t orow = (size_t)(b * 2048 + s) * 1024 + h * 64;
#pragma unroll
    for (int n = 0; n < 4; ++n) {
      uint2 ov;
      ov.x = pk2bf(oB[n][0] * inv, oB[n][1] * inv);
      ov.y = pk2bf(oB[n][2] * inv, oB[n][3] * inv);
      *(uint2*)(Oc + orow + n * 16 + quad * 4) = ov;
    }
  }
  {
    float inv = 1.f / lA_i;
    int s = tA * 64 + wave * 16 + l15;
    size_t orow = (size_t)(b * 2048 + s) * 1024 + h * 64;
#pragma unroll
    for (int n = 0; n < 4; ++n) {
      uint2 ov;
      ov.x = pk2bf(oA[n][0] * inv, oA[n][1] * inv);
      ov.y = pk2bf(oA[n][2] * inv, oA[n][3] * inv);
      *(uint2*)(Oc + orow + n * 16 + quad * 4) = ov;
    }
  }
}

// ---------------------------------------------------------------------------
extern "C" void kernel_launch(void* const* d_in, const int* in_sizes, int n_in,
                              void* d_out, int out_size, void* d_ws, size_t ws_size,
                              hipStream_t stream) {
  const float* x  = (const float*)d_in[0];
  const int* tokpos = (const int*)d_in[1];
  const float* Wq = (const float*)d_in[2];
  const float* Wk = (const float*)d_in[3];
  const float* Wv = (const float*)d_in[4];
  const float* Wo = (const float*)d_in[5];
  float* out = (float*)d_out;

  float* ws = (float*)d_ws;
  float* ctab = ws;
  float* stab = ctab + 65536;
  unsigned short* u = (unsigned short*)(stab + 65536);
  unsigned short* Qb  = u;
  unsigned short* Kb  = Qb + 4194304;
  unsigned short* Vb  = Kb + 4194304;   // transposed [bh][d][s]
  unsigned short* Oc  = Vb + 4194304;
  unsigned short* xb  = Oc + 4194304;
  unsigned short* Wqb = xb + 4194304;
  unsigned short* Wkb = Wqb + 1048576;
  unsigned short* Wvb = Wkb + 1048576;
  unsigned short* Wob = Wvb + 1048576;

  cvt_all<<<dim3(4096, 6), 256, 0, stream>>>(
      (const float4*)x, (const float4*)Wq, (const float4*)Wk,
      (const float4*)Wv, (const float4*)Wo,
      (ushort4*)xb, (ushort4*)Wqb, (ushort4*)Wkb, (ushort4*)Wvb, (ushort4*)Wob,
      tokpos, ctab, stab);

  qkv_mfma<<<dim3(32, 8, 3), 256, 0, stream>>>(
      xb, Wqb, Wkb, Wvb, ctab, stab, Qb, Kb, Vb);
  attn_flash<<<dim3(512), 256, 0, stream>>>(Qb, Kb, Vb, Oc);
  oproj_mfma<<<dim3(64, 8), 256, 0, stream>>>(Oc, Wob, out);
}

// Round 4
// 174.552 us; speedup vs baseline: 1.1169x; 1.0294x over previous
//
#include <hip/hip_runtime.h>
#include <hip/hip_bf16.h>

// B=2, S=2048, D=1024, H=16, DK=64, THETA=10000
// Inputs fp32 (positions int32): x[2,2048,1024], token_positions[2048],
// Wq,Wk,Wv,Wo [1024,1024].  Output fp32 [2,2048,1024].
// proj: y[b,s,o] = sum_d x[b,s,d] * W[o,d]

typedef __attribute__((ext_vector_type(8))) short short8;   // 8 bf16 = 4 VGPRs
typedef __attribute__((ext_vector_type(4))) float floatx4;  // MFMA accumulator

static __device__ __forceinline__ unsigned short f2bf(float f) {
  __hip_bfloat16 h = __float2bfloat16(f);
  return *(unsigned short*)&h;
}

// pack 2 floats -> 2 bf16 in one u32 (half-up rounding + v_perm byte pick).
// low ushort = bf16(a), high ushort = bf16(b). Finite inputs only.
static __device__ __forceinline__ unsigned int pk2bf(float a, float b) {
  unsigned int ua = __float_as_uint(a) + 0x8000u;
  unsigned int ub = __float_as_uint(b) + 0x8000u;
  return __builtin_amdgcn_perm(ub, ua, 0x07060302u);
}

// raw v_exp_f32 (2^x), single VALU transcendental; s_nop covers the
// trans->VALU dependency wait state.
static __device__ __forceinline__ float fexp2(float x) {
  float r;
  asm("v_exp_f32 %0, %1\n\ts_nop 0" : "=v"(r) : "v"(x));
  return r;
}

// async global->LDS DMA, 16 B per lane; lds base must be wave-uniform,
// HW writes lane i at ldsbase + i*16.
static __device__ __forceinline__ void gl2lds16(const unsigned short* g,
                                                unsigned short* l) {
  __builtin_amdgcn_global_load_lds(
      (const __attribute__((address_space(1))) void*)g,
      (__attribute__((address_space(3))) void*)l, 16, 0, 0);
}

// ---------------------------------------------------------------------------
// fp32 -> bf16 conversion for all 5 tensors + RoPE table gen, one launch.
// blockIdx.y: 0=x 1=Wq 2=Wk 3=Wv 4=Wo 5=rope tables
// ---------------------------------------------------------------------------
__global__ __launch_bounds__(256) void cvt_all(
    const float4* __restrict__ x,  const float4* __restrict__ wq,
    const float4* __restrict__ wk, const float4* __restrict__ wv,
    const float4* __restrict__ wo,
    ushort4* __restrict__ xb,  ushort4* __restrict__ wqb,
    ushort4* __restrict__ wkb, ushort4* __restrict__ wvb,
    ushort4* __restrict__ wob,
    const int* __restrict__ tokpos,
    float* __restrict__ ctab, float* __restrict__ stab) {
  int t = blockIdx.y;
  int i = blockIdx.x * 256 + threadIdx.x;
  if (t == 5) {
    if (i < 65536) {     // 2048 positions x 32 pair-freqs
      int s = i >> 5, f = i & 31;
      float inv = expf(-9.210340371976184f * (float)(2 * f) / 64.0f);
      float ang = (float)tokpos[s] * inv;
      ctab[i] = cosf(ang);
      stab[i] = sinf(ang);
    }
    return;
  }
  const float4* s = (t == 0) ? x : (t == 1) ? wq : (t == 2) ? wk : (t == 3) ? wv : wo;
  ushort4* d = (t == 0) ? xb : (t == 1) ? wqb : (t == 2) ? wkb : (t == 3) ? wvb : wob;
  int n4 = (t == 0) ? 1048576 : 262144;
  if (i < n4) {
    float4 v = s[i];
    ushort4 o;
    o.x = f2bf(v.x); o.y = f2bf(v.y); o.z = f2bf(v.z); o.w = f2bf(v.w);
    d[i] = o;
  }
}

// ---------------------------------------------------------------------------
// QKV projection R13: 64x128 tiles (oproj geometry) + R11 counted-vmcnt
// depth-2 pipeline + fused RoPE epilogue.
// R3 diagnosis: 128x128 tiles @64KB LDS -> 2 blocks/CU, 768 blocks = 1.5
// dispatch rounds -> ~25% slot-idle tail + TLP only 2 (Occupancy 14.7%,
// MfmaUtil 20%, all pipes low = latency/slot-bound).
// Now: LDS 48KB -> 3 blocks/CU; grid 64x8x3 = 1536 blocks = exactly 2
// uniform rounds of 768 resident.  BK=64 keeps the verified conflict-free
// 8-chunk XOR swizzle (BK=32 would shrink swizzle domain to 4 -> 4-way
// read conflict).  Pipeline schedule per K-step (6 DMA loads/thread/tile):
//   compute(slot kt&1)
//   s_barrier                      (A) all waves done reading slot kt&1
//   issue L(kt+2) -> slot kt&1     6 loads, in flight ~1.5 iters
//   s_waitcnt vmcnt(6)             waits ONLY for L(kt+1)
//   s_barrier                      (B) other slot ready on all waves
// Q pre-scaled by (1/sqrt(64))*log2(e) so attention uses raw v_exp_f32.
// Q,K bf16 [bh][s][64]; V transposed [bh][d][2048].
// ---------------------------------------------------------------------------
__global__ __launch_bounds__(256) void qkv_mfma(
    const unsigned short* __restrict__ X,
    const unsigned short* __restrict__ Wq,
    const unsigned short* __restrict__ Wk,
    const unsigned short* __restrict__ Wv,
    const float* __restrict__ ctab, const float* __restrict__ stab,
    unsigned short* __restrict__ Qo, unsigned short* __restrict__ Ko,
    unsigned short* __restrict__ Vo) {
  int mat = blockIdx.z;  // 0=q 1=k 2=v
  const unsigned short* W = (mat == 0) ? Wq : ((mat == 1) ? Wk : Wv);
  unsigned short* Out = (mat == 0) ? Qo : ((mat == 1) ? Ko : Vo);
  int m0 = blockIdx.x * 64, n0 = blockIdx.y * 128;

  __shared__ __align__(16) unsigned short lA[2][64 * 64];
  __shared__ __align__(16) unsigned short lB[2][128 * 64];
  int tid = threadIdx.x;
  int wave = tid >> 6, lane = tid & 63;
  int l15 = lane & 15, quad = lane >> 4;
  int rsub = lane >> 3, sch = lane & 7;
  int fsw = l15 & 7;

  floatx4 acc[4][2];
#pragma unroll
  for (int m = 0; m < 4; ++m)
#pragma unroll
    for (int n = 0; n < 2; ++n) acc[m][n] = (floatx4){0.f, 0.f, 0.f, 0.f};

  // prologue: L(0)->slot0 (6 loads), L(1)->slot1 (6 loads)
#pragma unroll
  for (int kp = 0; kp < 2; ++kp) {
#pragma unroll
    for (int p = 0; p < 2; ++p) {
      int r = wave * 16 + p * 8 + rsub;
      int g = sch ^ (r & 7);
      gl2lds16(X + (size_t)(m0 + r) * 1024 + kp * 64 + g * 8,
               lA[kp] + (wave * 16 + p * 8) * 64);
    }
#pragma unroll
    for (int p = 0; p < 4; ++p) {
      int r = wave * 32 + p * 8 + rsub;
      int g = sch ^ (r & 7);
      gl2lds16(W + (size_t)(n0 + r) * 1024 + kp * 64 + g * 8,
               lB[kp] + (wave * 32 + p * 8) * 64);
    }
  }
  asm volatile("s_waitcnt vmcnt(6)" ::: "memory");  // L(0) done
  __builtin_amdgcn_s_barrier();

  for (int kt = 0; kt < 16; ++kt) {
    int cur = kt & 1;
#pragma unroll
    for (int ks = 0; ks < 2; ++ks) {
      int slot = ((ks * 4 + quad) ^ fsw) * 8;
      short8 af[4], bf[2];
#pragma unroll
      for (int m = 0; m < 4; ++m)
        af[m] = *(const short8*)(lA[cur] + (m * 16 + l15) * 64 + slot);
#pragma unroll
      for (int n = 0; n < 2; ++n)
        bf[n] = *(const short8*)(lB[cur] + (wave * 32 + n * 16 + l15) * 64 + slot);
#pragma unroll
      for (int m = 0; m < 4; ++m)
#pragma unroll
        for (int n = 0; n < 2; ++n)
          acc[m][n] = __builtin_amdgcn_mfma_f32_16x16x32_bf16(
              af[m], bf[n], acc[m][n], 0, 0, 0);
    }
    if (kt == 15) break;
    __builtin_amdgcn_s_barrier();  // (A)
    if (kt < 14) {
#pragma unroll
      for (int p = 0; p < 2; ++p) {
        int r = wave * 16 + p * 8 + rsub;
        int g = sch ^ (r & 7);
        gl2lds16(X + (size_t)(m0 + r) * 1024 + (kt + 2) * 64 + g * 8,
                 lA[cur] + (wave * 16 + p * 8) * 64);
      }
#pragma unroll
      for (int p = 0; p < 4; ++p) {
        int r = wave * 32 + p * 8 + rsub;
        int g = sch ^ (r & 7);
        gl2lds16(W + (size_t)(n0 + r) * 1024 + (kt + 2) * 64 + g * 8,
                 lB[cur] + (wave * 32 + p * 8) * 64);
      }
      asm volatile("s_waitcnt vmcnt(6)" ::: "memory");  // L(kt+1) done
    } else {
      asm volatile("s_waitcnt vmcnt(0)" ::: "memory");  // drain L(15)
    }
    __builtin_amdgcn_s_barrier();  // (B)
  }

  // ---- fused RoPE / transpose epilogue (wave owns 32 cols, 64 rows)
#pragma unroll
  for (int n = 0; n < 2; ++n) {
    int col = n0 + wave * 32 + n * 16 + l15;  // 0..1023
    int h = col >> 6;
    int d = col & 63;
    int pi = d >> 1;
    bool odd = (d & 1) != 0;
    size_t hb = (size_t)h * 2048 * 64;
#pragma unroll
    for (int m = 0; m < 4; ++m) {
      int row0 = m0 + m * 16 + quad * 4;  // rows row0..row0+3
      int b = row0 >> 11;
      int s0 = row0 & 2047;
      size_t base = (size_t)b * 16 * 2048 * 64 + hb;
      if (mat == 2) {
        // V: packed b64 store along s (transposed layout [d][s])
        ushort4 pv;
        pv.x = f2bf(acc[m][n][0]);
        pv.y = f2bf(acc[m][n][1]);
        pv.z = f2bf(acc[m][n][2]);
        pv.w = f2bf(acc[m][n][3]);
        *(ushort4*)(Out + base + (size_t)d * 2048 + s0) = pv;
      } else {
#pragma unroll
        for (int i = 0; i < 4; ++i) {
          int s = s0 + i;
          float v = acc[m][n][i];
          float p = __shfl_xor(v, 1);
          float c = ctab[s * 32 + pi];
          float sn = stab[s * 32 + pi];
          float res = odd ? fmaf(p, sn, v * c) : fmaf(v, c, -p * sn);
          if (mat == 0) res *= 0.1803368801111204f;  // 0.125 * log2(e)
          Out[base + (size_t)s * 64 + d] = f2bf(res);
        }
      }
    }
  }
}

// ---------------------------------------------------------------------------
// Output projection: out = Oc @ Wo^T.  64x128 tiles -> 512 blocks (2/CU).
// Depth-2 counted-vmcnt pipeline (R11); 6 DMA loads/thread per tile ->
// vmcnt(6).  fp32 store.
// ---------------------------------------------------------------------------
__global__ __launch_bounds__(256) void oproj_mfma(
    const unsigned short* __restrict__ A, const unsigned short* __restrict__ Wo,
    float* __restrict__ Out) {
  __shared__ __align__(16) unsigned short lA[2][64 * 64];
  __shared__ __align__(16) unsigned short lB[2][128 * 64];
  int tid = threadIdx.x;
  int wave = tid >> 6, lane = tid & 63;
  int l15 = lane & 15, quad = lane >> 4;
  int rsub = lane >> 3, sch = lane & 7;
  int fsw = l15 & 7;
  int m0 = blockIdx.x * 64, n0 = blockIdx.y * 128;

  floatx4 acc[4][2];
#pragma unroll
  for (int m = 0; m < 4; ++m)
#pragma unroll
    for (int n = 0; n < 2; ++n) acc[m][n] = (floatx4){0.f, 0.f, 0.f, 0.f};

  // prologue: L(0)->slot0 (6 loads), L(1)->slot1 (6 loads)
#pragma unroll
  for (int kp = 0; kp < 2; ++kp) {
#pragma unroll
    for (int p = 0; p < 2; ++p) {
      int r = wave * 16 + p * 8 + rsub;
      int g = sch ^ (r & 7);
      gl2lds16(A + (size_t)(m0 + r) * 1024 + kp * 64 + g * 8,
               lA[kp] + (wave * 16 + p * 8) * 64);
    }
#pragma unroll
    for (int p = 0; p < 4; ++p) {
      int r = wave * 32 + p * 8 + rsub;
      int g = sch ^ (r & 7);
      gl2lds16(Wo + (size_t)(n0 + r) * 1024 + kp * 64 + g * 8,
               lB[kp] + (wave * 32 + p * 8) * 64);
    }
  }
  asm volatile("s_waitcnt vmcnt(6)" ::: "memory");  // L(0) done
  __builtin_amdgcn_s_barrier();

  for (int kt = 0; kt < 16; ++kt) {
    int cur = kt & 1;
#pragma unroll
    for (int ks = 0; ks < 2; ++ks) {
      int slot = ((ks * 4 + quad) ^ fsw) * 8;
      short8 af[4], bf[2];
#pragma unroll
      for (int m = 0; m < 4; ++m)
        af[m] = *(const short8*)(lA[cur] + (m * 16 + l15) * 64 + slot);
#pragma unroll
      for (int n = 0; n < 2; ++n)
        bf[n] = *(const short8*)(lB[cur] + (wave * 32 + n * 16 + l15) * 64 + slot);
#pragma unroll
      for (int m = 0; m < 4; ++m)
#pragma unroll
        for (int n = 0; n < 2; ++n)
          acc[m][n] = __builtin_amdgcn_mfma_f32_16x16x32_bf16(
              af[m], bf[n], acc[m][n], 0, 0, 0);
    }
    if (kt == 15) break;
    __builtin_amdgcn_s_barrier();  // (A)
    if (kt < 14) {
#pragma unroll
      for (int p = 0; p < 2; ++p) {
        int r = wave * 16 + p * 8 + rsub;
        int g = sch ^ (r & 7);
        gl2lds16(A + (size_t)(m0 + r) * 1024 + (kt + 2) * 64 + g * 8,
                 lA[cur] + (wave * 16 + p * 8) * 64);
      }
#pragma unroll
      for (int p = 0; p < 4; ++p) {
        int r = wave * 32 + p * 8 + rsub;
        int g = sch ^ (r & 7);
        gl2lds16(Wo + (size_t)(n0 + r) * 1024 + (kt + 2) * 64 + g * 8,
                 lB[cur] + (wave * 32 + p * 8) * 64);
      }
      asm volatile("s_waitcnt vmcnt(6)" ::: "memory");  // L(kt+1) done
    } else {
      asm volatile("s_waitcnt vmcnt(0)" ::: "memory");  // drain L(15)
    }
    __builtin_amdgcn_s_barrier();  // (B)
  }

#pragma unroll
  for (int m = 0; m < 4; ++m) {
#pragma unroll
    for (int n = 0; n < 2; ++n) {
      int col = n0 + wave * 32 + n * 16 + l15;
#pragma unroll
      for (int i = 0; i < 4; ++i) {
        int row = m0 + m * 16 + quad * 4 + i;
        Out[(size_t)row * 1024 + col] = acc[m][n][i];
      }
    }
  }
}

// ---------------------------------------------------------------------------
// Flash attention R12: dual-stream uniform blocks.
// One block processes the PAIR of q-tiles (x, 31-x).  Both streams consume
// the SAME staged kv-tile kt each iter (A active kt<=x, B always), so every
// block is exactly 33 work-units (uniform -> sustained residency), staging+
// barriers are shared, and each wave carries TWO independent chains whose
// latencies mutually hide.  Grid 512 (2/CU sustained).  XCD-clustered id:
// id%8 = bh>>2 so each bh's 512KB K/V stays in one XCD L2.
// Measured R3: attn left top-5 (was 51us x5 in R2).
// ---------------------------------------------------------------------------
#define LPS 72  // lP row stride

static __device__ __forceinline__ void qk_step(
    const unsigned short* lK, int l15, int c0, int c1,
    short8 q0, short8 q1, floatx4 (&sc)[4]) {
#pragma unroll
  for (int sub = 0; sub < 4; ++sub) {
    const unsigned short* kr = lK + (sub * 16 + l15) * 64;
    short8 a0 = *(const short8*)(kr + c0);
    short8 a1 = *(const short8*)(kr + c1);
    floatx4 s = {0.f, 0.f, 0.f, 0.f};
    s = __builtin_amdgcn_mfma_f32_16x16x32_bf16(a0, q0, s, 0, 0, 0);
    s = __builtin_amdgcn_mfma_f32_16x16x32_bf16(a1, q1, s, 0, 0, 0);
    sc[sub] = s;
  }
}

static __device__ __forceinline__ void sm_step(
    floatx4 (&sc)[4], float& m_i, float& l_i, floatx4 (&o)[4],
    bool diag, int qin, int quad) {
  if (diag) {  // causal mask on diagonal tile: k-within > q-within
#pragma unroll
    for (int sub = 0; sub < 4; ++sub)
#pragma unroll
      for (int i = 0; i < 4; ++i)
        if (sub * 16 + quad * 4 + i > qin) sc[sub][i] = -1e30f;
  }
  float mb = sc[0][0];
#pragma unroll
  for (int sub = 0; sub < 4; ++sub)
#pragma unroll
    for (int i = 0; i < 4; ++i) mb = fmaxf(mb, sc[sub][i]);
  mb = fmaxf(mb, __shfl_xor(mb, 16));
  mb = fmaxf(mb, __shfl_xor(mb, 32));

  float mn = fmaxf(m_i, mb);
  float al = fexp2(m_i - mn);
  m_i = mn;
  float rs = 0.f;
#pragma unroll
  for (int sub = 0; sub < 4; ++sub)
#pragma unroll
    for (int i = 0; i < 4; ++i) {
      float p = fexp2(sc[sub][i] - mn);
      sc[sub][i] = p;
      rs += p;
    }
  rs += __shfl_xor(rs, 16);
  rs += __shfl_xor(rs, 32);
  l_i = l_i * al + rs;
#pragma unroll
  for (int n = 0; n < 4; ++n) {
    o[n][0] *= al; o[n][1] *= al; o[n][2] *= al; o[n][3] *= al;
  }
}

static __device__ __forceinline__ void pv_step(
    const floatx4 (&sc)[4], floatx4 (&o)[4], unsigned short* lPw,
    const unsigned short* lV, int l15, int quad, int c0, int c1) {
  unsigned short* pw = lPw + l15 * LPS;
#pragma unroll
  for (int sub = 0; sub < 4; ++sub) {
    uint2 w;
    w.x = pk2bf(sc[sub][0], sc[sub][1]);
    w.y = pk2bf(sc[sub][2], sc[sub][3]);
    *(uint2*)(pw + sub * 16 + quad * 4) = w;
  }
  const unsigned short* pr = lPw + l15 * LPS + quad * 8;
  short8 pa0 = *(const short8*)(pr);
  short8 pa1 = *(const short8*)(pr + 32);
#pragma unroll
  for (int n = 0; n < 4; ++n) {
    const unsigned short* vr = lV + (n * 16 + l15) * 64;
    short8 vb0 = *(const short8*)(vr + c0);
    short8 vb1 = *(const short8*)(vr + c1);
    o[n] = __builtin_amdgcn_mfma_f32_16x16x32_bf16(vb0, pa0, o[n], 0, 0, 0);
    o[n] = __builtin_amdgcn_mfma_f32_16x16x32_bf16(vb1, pa1, o[n], 0, 0, 0);
  }
}

__global__ __launch_bounds__(256, 2) void attn_flash(
    const unsigned short* __restrict__ Q, const unsigned short* __restrict__ K,
    const unsigned short* __restrict__ Vt, unsigned short* __restrict__ Oc) {
  __shared__ __align__(16) unsigned short lK[64 * 64];   // [kj][d] swizzled
  __shared__ __align__(16) unsigned short lV[64 * 64];   // [d][kj] swizzled
  __shared__ unsigned short lP[8][16 * LPS];             // [wave*2+stream]

  int tid = threadIdx.x;
  int wave = tid >> 6, lane = tid & 63;
  int l15 = lane & 15, quad = lane >> 4;

  // XCD-clustered decode: id%8 = bh>>2 (4 bh per XCD -> K/V L2-resident)
  int id = blockIdx.x;              // 0..511
  int rest = id >> 3;               // 0..63
  int pair = rest >> 2;             // 0..15
  int bh = (id & 7) * 4 + (rest & 3);
  int tA = pair;                    // small tile
  int tB = 31 - pair;               // big tile (always active)
  int NT = tB + 1;                  // kv tiles this block

  size_t base = (size_t)bh * 2048 * 64;

  // Q fragments (B-operand, loop-invariant) for both streams
  const unsigned short* qrowA = Q + base + (size_t)(tA * 64 + wave * 16 + l15) * 64;
  const unsigned short* qrowB = Q + base + (size_t)(tB * 64 + wave * 16 + l15) * 64;
  short8 qA0 = *(const short8*)(qrowA + quad * 8);
  short8 qA1 = *(const short8*)(qrowA + 32 + quad * 8);
  short8 qB0 = *(const short8*)(qrowB + quad * 8);
  short8 qB1 = *(const short8*)(qrowB + 32 + quad * 8);

  floatx4 oA[4], oB[4];
  float mA_i = -1e30f, lA_i = 0.f, mB_i = -1e30f, lB_i = 0.f;
#pragma unroll
  for (int n = 0; n < 4; ++n) {
    oA[n] = (floatx4){0.f, 0.f, 0.f, 0.f};
    oB[n] = (floatx4){0.f, 0.f, 0.f, 0.f};
  }

  // staging: thread covers rows r0,r1 (r1=r0+32, same &7), global chunk g
  int r0 = tid >> 3, g = tid & 7;
  int r1 = r0 + 32;
  int e0 = g * 8;                       // global element offset of chunk g
  int sl = (g ^ (r0 & 7)) * 8;          // swizzled LDS slot (element offset)
  int fsw = l15 & 7;                    // fragment-read swizzle
  int c0 = (quad ^ fsw) * 8;            // slot of global chunk quad
  int c1 = ((quad + 4) ^ fsw) * 8;      // slot of global chunk quad+4

  // prefetch kt=0
  const unsigned short* kp = K + base;
  const unsigned short* vp = Vt + base;
  short8 pk0 = *(const short8*)(kp + r0 * 64 + e0);
  short8 pk1 = *(const short8*)(kp + r1 * 64 + e0);
  short8 pv0 = *(const short8*)(vp + (size_t)r0 * 2048 + e0);
  short8 pv1 = *(const short8*)(vp + (size_t)r1 * 2048 + e0);

  int qin = wave * 16 + l15;  // q-row within tile (for diagonal mask)

  for (int kt = 0; kt < NT; ++kt) {
    bool aAct = (kt <= tA);

    __syncthreads();   // all waves done reading lK/lV from previous iter
    *(short8*)(lK + r0 * 64 + sl) = pk0;
    *(short8*)(lK + r1 * 64 + sl) = pk1;
    *(short8*)(lV + r0 * 64 + sl) = pv0;
    *(short8*)(lV + r1 * 64 + sl) = pv1;
    __syncthreads();

    if (kt + 1 < NT) {  // prefetch next tile; consumed at next iter's write
      const unsigned short* kn = K + base + (size_t)(kt + 1) * 4096;
      const unsigned short* vn = Vt + base + (kt + 1) * 64;
      pk0 = *(const short8*)(kn + r0 * 64 + e0);
      pk1 = *(const short8*)(kn + r1 * 64 + e0);
      pv0 = *(const short8*)(vn + (size_t)r0 * 2048 + e0);
      pv1 = *(const short8*)(vn + (size_t)r1 * 2048 + e0);
    }

    // ---- dual-stream compute: B always, A while kt <= tA.  Phases ordered
    // so stream A's MFMAs queue while stream B's softmax VALU chain runs.
    floatx4 scB[4], scA[4];
    qk_step(lK, l15, c0, c1, qB0, qB1, scB);
    if (aAct) qk_step(lK, l15, c0, c1, qA0, qA1, scA);

    sm_step(scB, mB_i, lB_i, oB, kt == NT - 1, qin, quad);
    if (aAct) sm_step(scA, mA_i, lA_i, oA, kt == tA, qin, quad);

    pv_step(scB, oB, lP[wave * 2], lV, l15, quad, c0, c1);
    if (aAct) pv_step(scA, oA, lP[wave * 2 + 1], lV, l15, quad, c0, c1);
  }

  // ---- epilogue: per-lane 1/l, packed b64 stores for both streams
  int b = bh >> 4, h = bh & 15;
  {
    float inv = 1.f / lB_i;
    int s = tB * 64 + wave * 16 + l15;
    size_t orow = (size_t)(b * 2048 + s) * 1024 + h * 64;
#pragma unroll
    for (int n = 0; n < 4; ++n) {
      uint2 ov;
      ov.x = pk2bf(oB[n][0] * inv, oB[n][1] * inv);
      ov.y = pk2bf(oB[n][2] * inv, oB[n][3] * inv);
      *(uint2*)(Oc + orow + n * 16 + quad * 4) = ov;
    }
  }
  {
    float inv = 1.f / lA_i;
    int s = tA * 64 + wave * 16 + l15;
    size_t orow = (size_t)(b * 2048 + s) * 1024 + h * 64;
#pragma unroll
    for (int n = 0; n < 4; ++n) {
      uint2 ov;
      ov.x = pk2bf(oA[n][0] * inv, oA[n][1] * inv);
      ov.y = pk2bf(oA[n][2] * inv, oA[n][3] * inv);
      *(uint2*)(Oc + orow + n * 16 + quad * 4) = ov;
    }
  }
}

// ---------------------------------------------------------------------------
extern "C" void kernel_launch(void* const* d_in, const int* in_sizes, int n_in,
                              void* d_out, int out_size, void* d_ws, size_t ws_size,
                              hipStream_t stream) {
  const float* x  = (const float*)d_in[0];
  const int* tokpos = (const int*)d_in[1];
  const float* Wq = (const float*)d_in[2];
  const float* Wk = (const float*)d_in[3];
  const float* Wv = (const float*)d_in[4];
  const float* Wo = (const float*)d_in[5];
  float* out = (float*)d_out;

  float* ws = (float*)d_ws;
  float* ctab = ws;
  float* stab = ctab + 65536;
  unsigned short* u = (unsigned short*)(stab + 65536);
  unsigned short* Qb  = u;
  unsigned short* Kb  = Qb + 4194304;
  unsigned short* Vb  = Kb + 4194304;   // transposed [bh][d][s]
  unsigned short* Oc  = Vb + 4194304;
  unsigned short* xb  = Oc + 4194304;
  unsigned short* Wqb = xb + 4194304;
  unsigned short* Wkb = Wqb + 1048576;
  unsigned short* Wvb = Wkb + 1048576;
  unsigned short* Wob = Wvb + 1048576;

  cvt_all<<<dim3(4096, 6), 256, 0, stream>>>(
      (const float4*)x, (const float4*)Wq, (const float4*)Wk,
      (const float4*)Wv, (const float4*)Wo,
      (ushort4*)xb, (ushort4*)Wqb, (ushort4*)Wkb, (ushort4*)Wvb, (ushort4*)Wob,
      tokpos, ctab, stab);

  qkv_mfma<<<dim3(64, 8, 3), 256, 0, stream>>>(
      xb, Wqb, Wkb, Wvb, ctab, stab, Qb, Kb, Vb);
  attn_flash<<<dim3(512), 256, 0, stream>>>(Qb, Kb, Vb, Oc);
  oproj_mfma<<<dim3(64, 8), 256, 0, stream>>>(Oc, Wob, out);
}

// Round 5
// 174.021 us; speedup vs baseline: 1.1203x; 1.0031x over previous
//
#include <hip/hip_runtime.h>
#include <hip/hip_bf16.h>

// B=2, S=2048, D=1024, H=16, DK=64, THETA=10000
// Inputs fp32 (positions int32): x[2,2048,1024], token_positions[2048],
// Wq,Wk,Wv,Wo [1024,1024].  Output fp32 [2,2048,1024].
// proj: y[b,s,o] = sum_d x[b,s,d] * W[o,d]

typedef __attribute__((ext_vector_type(8))) short short8;   // 8 bf16 = 4 VGPRs
typedef __attribute__((ext_vector_type(4))) float floatx4;  // MFMA accumulator

static __device__ __forceinline__ unsigned short f2bf(float f) {
  __hip_bfloat16 h = __float2bfloat16(f);
  return *(unsigned short*)&h;
}

// pack 2 floats -> 2 bf16 in one u32 (half-up rounding + v_perm byte pick).
// low ushort = bf16(a), high ushort = bf16(b). Finite inputs only.
static __device__ __forceinline__ unsigned int pk2bf(float a, float b) {
  unsigned int ua = __float_as_uint(a) + 0x8000u;
  unsigned int ub = __float_as_uint(b) + 0x8000u;
  return __builtin_amdgcn_perm(ub, ua, 0x07060302u);
}

// raw v_exp_f32 (2^x), single VALU transcendental; s_nop covers the
// trans->VALU dependency wait state.
static __device__ __forceinline__ float fexp2(float x) {
  float r;
  asm("v_exp_f32 %0, %1\n\ts_nop 0" : "=v"(r) : "v"(x));
  return r;
}

// async global->LDS DMA, 16 B per lane; lds base must be wave-uniform,
// HW writes lane i at ldsbase + i*16.
static __device__ __forceinline__ void gl2lds16(const unsigned short* g,
                                                unsigned short* l) {
  __builtin_amdgcn_global_load_lds(
      (const __attribute__((address_space(1))) void*)g,
      (__attribute__((address_space(3))) void*)l, 16, 0, 0);
}

// ---------------------------------------------------------------------------
// fp32 -> bf16 conversion for all 5 tensors + RoPE table gen, one launch.
// blockIdx.y: 0=x 1=Wq 2=Wk 3=Wv 4=Wo 5=rope tables
// ---------------------------------------------------------------------------
__global__ __launch_bounds__(256) void cvt_all(
    const float4* __restrict__ x,  const float4* __restrict__ wq,
    const float4* __restrict__ wk, const float4* __restrict__ wv,
    const float4* __restrict__ wo,
    ushort4* __restrict__ xb,  ushort4* __restrict__ wqb,
    ushort4* __restrict__ wkb, ushort4* __restrict__ wvb,
    ushort4* __restrict__ wob,
    const int* __restrict__ tokpos,
    float* __restrict__ ctab, float* __restrict__ stab) {
  int t = blockIdx.y;
  int i = blockIdx.x * 256 + threadIdx.x;
  if (t == 5) {
    if (i < 65536) {     // 2048 positions x 32 pair-freqs
      int s = i >> 5, f = i & 31;
      float inv = expf(-9.210340371976184f * (float)(2 * f) / 64.0f);
      float ang = (float)tokpos[s] * inv;
      ctab[i] = cosf(ang);
      stab[i] = sinf(ang);
    }
    return;
  }
  const float4* s = (t == 0) ? x : (t == 1) ? wq : (t == 2) ? wk : (t == 3) ? wv : wo;
  ushort4* d = (t == 0) ? xb : (t == 1) ? wqb : (t == 2) ? wkb : (t == 3) ? wvb : wob;
  int n4 = (t == 0) ? 1048576 : 262144;
  if (i < n4) {
    float4 v = s[i];
    ushort4 o;
    o.x = f2bf(v.x); o.y = f2bf(v.y); o.z = f2bf(v.z); o.w = f2bf(v.w);
    d[i] = o;
  }
}

// ---------------------------------------------------------------------------
// QKV projection R13: 64x128 tiles + R11 counted-vmcnt depth-2 pipeline +
// fused RoPE epilogue.  LDS 48KB -> 3 blocks/CU; grid 64x8x3 = 1536 blocks
// = exactly 2 uniform rounds of 768 resident.  BK=64 keeps the verified
// conflict-free 8-chunk XOR swizzle.  Measured R4: qkv left top-5.
// Q pre-scaled by (1/sqrt(64))*log2(e) so attention uses raw v_exp_f32.
// Q,K bf16 [bh][s][64]; V transposed [bh][d][2048].
// ---------------------------------------------------------------------------
__global__ __launch_bounds__(256) void qkv_mfma(
    const unsigned short* __restrict__ X,
    const unsigned short* __restrict__ Wq,
    const unsigned short* __restrict__ Wk,
    const unsigned short* __restrict__ Wv,
    const float* __restrict__ ctab, const float* __restrict__ stab,
    unsigned short* __restrict__ Qo, unsigned short* __restrict__ Ko,
    unsigned short* __restrict__ Vo) {
  int mat = blockIdx.z;  // 0=q 1=k 2=v
  const unsigned short* W = (mat == 0) ? Wq : ((mat == 1) ? Wk : Wv);
  unsigned short* Out = (mat == 0) ? Qo : ((mat == 1) ? Ko : Vo);
  int m0 = blockIdx.x * 64, n0 = blockIdx.y * 128;

  __shared__ __align__(16) unsigned short lA[2][64 * 64];
  __shared__ __align__(16) unsigned short lB[2][128 * 64];
  int tid = threadIdx.x;
  int wave = tid >> 6, lane = tid & 63;
  int l15 = lane & 15, quad = lane >> 4;
  int rsub = lane >> 3, sch = lane & 7;
  int fsw = l15 & 7;

  floatx4 acc[4][2];
#pragma unroll
  for (int m = 0; m < 4; ++m)
#pragma unroll
    for (int n = 0; n < 2; ++n) acc[m][n] = (floatx4){0.f, 0.f, 0.f, 0.f};

  // prologue: L(0)->slot0 (6 loads), L(1)->slot1 (6 loads)
#pragma unroll
  for (int kp = 0; kp < 2; ++kp) {
#pragma unroll
    for (int p = 0; p < 2; ++p) {
      int r = wave * 16 + p * 8 + rsub;
      int g = sch ^ (r & 7);
      gl2lds16(X + (size_t)(m0 + r) * 1024 + kp * 64 + g * 8,
               lA[kp] + (wave * 16 + p * 8) * 64);
    }
#pragma unroll
    for (int p = 0; p < 4; ++p) {
      int r = wave * 32 + p * 8 + rsub;
      int g = sch ^ (r & 7);
      gl2lds16(W + (size_t)(n0 + r) * 1024 + kp * 64 + g * 8,
               lB[kp] + (wave * 32 + p * 8) * 64);
    }
  }
  asm volatile("s_waitcnt vmcnt(6)" ::: "memory");  // L(0) done
  __builtin_amdgcn_s_barrier();

  for (int kt = 0; kt < 16; ++kt) {
    int cur = kt & 1;
#pragma unroll
    for (int ks = 0; ks < 2; ++ks) {
      int slot = ((ks * 4 + quad) ^ fsw) * 8;
      short8 af[4], bf[2];
#pragma unroll
      for (int m = 0; m < 4; ++m)
        af[m] = *(const short8*)(lA[cur] + (m * 16 + l15) * 64 + slot);
#pragma unroll
      for (int n = 0; n < 2; ++n)
        bf[n] = *(const short8*)(lB[cur] + (wave * 32 + n * 16 + l15) * 64 + slot);
#pragma unroll
      for (int m = 0; m < 4; ++m)
#pragma unroll
        for (int n = 0; n < 2; ++n)
          acc[m][n] = __builtin_amdgcn_mfma_f32_16x16x32_bf16(
              af[m], bf[n], acc[m][n], 0, 0, 0);
    }
    if (kt == 15) break;
    __builtin_amdgcn_s_barrier();  // (A)
    if (kt < 14) {
#pragma unroll
      for (int p = 0; p < 2; ++p) {
        int r = wave * 16 + p * 8 + rsub;
        int g = sch ^ (r & 7);
        gl2lds16(X + (size_t)(m0 + r) * 1024 + (kt + 2) * 64 + g * 8,
                 lA[cur] + (wave * 16 + p * 8) * 64);
      }
#pragma unroll
      for (int p = 0; p < 4; ++p) {
        int r = wave * 32 + p * 8 + rsub;
        int g = sch ^ (r & 7);
        gl2lds16(W + (size_t)(n0 + r) * 1024 + (kt + 2) * 64 + g * 8,
                 lB[cur] + (wave * 32 + p * 8) * 64);
      }
      asm volatile("s_waitcnt vmcnt(6)" ::: "memory");  // L(kt+1) done
    } else {
      asm volatile("s_waitcnt vmcnt(0)" ::: "memory");  // drain L(15)
    }
    __builtin_amdgcn_s_barrier();  // (B)
  }

  // ---- fused RoPE / transpose epilogue (wave owns 32 cols, 64 rows)
#pragma unroll
  for (int n = 0; n < 2; ++n) {
    int col = n0 + wave * 32 + n * 16 + l15;  // 0..1023
    int h = col >> 6;
    int d = col & 63;
    int pi = d >> 1;
    bool odd = (d & 1) != 0;
    size_t hb = (size_t)h * 2048 * 64;
#pragma unroll
    for (int m = 0; m < 4; ++m) {
      int row0 = m0 + m * 16 + quad * 4;  // rows row0..row0+3
      int b = row0 >> 11;
      int s0 = row0 & 2047;
      size_t base = (size_t)b * 16 * 2048 * 64 + hb;
      if (mat == 2) {
        // V: packed b64 store along s (transposed layout [d][s])
        ushort4 pv;
        pv.x = f2bf(acc[m][n][0]);
        pv.y = f2bf(acc[m][n][1]);
        pv.z = f2bf(acc[m][n][2]);
        pv.w = f2bf(acc[m][n][3]);
        *(ushort4*)(Out + base + (size_t)d * 2048 + s0) = pv;
      } else {
#pragma unroll
        for (int i = 0; i < 4; ++i) {
          int s = s0 + i;
          float v = acc[m][n][i];
          float p = __shfl_xor(v, 1);
          float c = ctab[s * 32 + pi];
          float sn = stab[s * 32 + pi];
          float res = odd ? fmaf(p, sn, v * c) : fmaf(v, c, -p * sn);
          if (mat == 0) res *= 0.1803368801111204f;  // 0.125 * log2(e)
          Out[base + (size_t)s * 64 + d] = f2bf(res);
        }
      }
    }
  }
}

// ---------------------------------------------------------------------------
// Output projection: out = Oc @ Wo^T.  64x128 tiles -> 512 blocks (2/CU).
// Depth-2 counted-vmcnt pipeline (R11); 6 DMA loads/thread per tile ->
// vmcnt(6).  fp32 store.
// ---------------------------------------------------------------------------
__global__ __launch_bounds__(256) void oproj_mfma(
    const unsigned short* __restrict__ A, const unsigned short* __restrict__ Wo,
    float* __restrict__ Out) {
  __shared__ __align__(16) unsigned short lA[2][64 * 64];
  __shared__ __align__(16) unsigned short lB[2][128 * 64];
  int tid = threadIdx.x;
  int wave = tid >> 6, lane = tid & 63;
  int l15 = lane & 15, quad = lane >> 4;
  int rsub = lane >> 3, sch = lane & 7;
  int fsw = l15 & 7;
  int m0 = blockIdx.x * 64, n0 = blockIdx.y * 128;

  floatx4 acc[4][2];
#pragma unroll
  for (int m = 0; m < 4; ++m)
#pragma unroll
    for (int n = 0; n < 2; ++n) acc[m][n] = (floatx4){0.f, 0.f, 0.f, 0.f};

  // prologue: L(0)->slot0 (6 loads), L(1)->slot1 (6 loads)
#pragma unroll
  for (int kp = 0; kp < 2; ++kp) {
#pragma unroll
    for (int p = 0; p < 2; ++p) {
      int r = wave * 16 + p * 8 + rsub;
      int g = sch ^ (r & 7);
      gl2lds16(A + (size_t)(m0 + r) * 1024 + kp * 64 + g * 8,
               lA[kp] + (wave * 16 + p * 8) * 64);
    }
#pragma unroll
    for (int p = 0; p < 4; ++p) {
      int r = wave * 32 + p * 8 + rsub;
      int g = sch ^ (r & 7);
      gl2lds16(Wo + (size_t)(n0 + r) * 1024 + kp * 64 + g * 8,
               lB[kp] + (wave * 32 + p * 8) * 64);
    }
  }
  asm volatile("s_waitcnt vmcnt(6)" ::: "memory");  // L(0) done
  __builtin_amdgcn_s_barrier();

  for (int kt = 0; kt < 16; ++kt) {
    int cur = kt & 1;
#pragma unroll
    for (int ks = 0; ks < 2; ++ks) {
      int slot = ((ks * 4 + quad) ^ fsw) * 8;
      short8 af[4], bf[2];
#pragma unroll
      for (int m = 0; m < 4; ++m)
        af[m] = *(const short8*)(lA[cur] + (m * 16 + l15) * 64 + slot);
#pragma unroll
      for (int n = 0; n < 2; ++n)
        bf[n] = *(const short8*)(lB[cur] + (wave * 32 + n * 16 + l15) * 64 + slot);
#pragma unroll
      for (int m = 0; m < 4; ++m)
#pragma unroll
        for (int n = 0; n < 2; ++n)
          acc[m][n] = __builtin_amdgcn_mfma_f32_16x16x32_bf16(
              af[m], bf[n], acc[m][n], 0, 0, 0);
    }
    if (kt == 15) break;
    __builtin_amdgcn_s_barrier();  // (A)
    if (kt < 14) {
#pragma unroll
      for (int p = 0; p < 2; ++p) {
        int r = wave * 16 + p * 8 + rsub;
        int g = sch ^ (r & 7);
        gl2lds16(A + (size_t)(m0 + r) * 1024 + (kt + 2) * 64 + g * 8,
                 lA[cur] + (wave * 16 + p * 8) * 64);
      }
#pragma unroll
      for (int p = 0; p < 4; ++p) {
        int r = wave * 32 + p * 8 + rsub;
        int g = sch ^ (r & 7);
        gl2lds16(Wo + (size_t)(n0 + r) * 1024 + (kt + 2) * 64 + g * 8,
                 lB[cur] + (wave * 32 + p * 8) * 64);
      }
      asm volatile("s_waitcnt vmcnt(6)" ::: "memory");  // L(kt+1) done
    } else {
      asm volatile("s_waitcnt vmcnt(0)" ::: "memory");  // drain L(15)
    }
    __builtin_amdgcn_s_barrier();  // (B)
  }

#pragma unroll
  for (int m = 0; m < 4; ++m) {
#pragma unroll
    for (int n = 0; n < 2; ++n) {
      int col = n0 + wave * 32 + n * 16 + l15;
#pragma unroll
      for (int i = 0; i < 4; ++i) {
        int row = m0 + m * 16 + quad * 4 + i;
        Out[(size_t)row * 1024 + col] = acc[m][n][i];
      }
    }
  }
}

// ---------------------------------------------------------------------------
// Flash attention R14: half-tile dual-stream blocks, single raw barrier/iter.
// R4 diagnosis: latency-bound (MfmaUtil 14%, VALU 35%, HBM 5.6%, occ 17% of
// a 25% ceiling); ~1855cy/iter vs ~600cy issue.  Two __syncthreads per iter
// each lower to s_waitcnt vmcnt(0) lgkmcnt(0) + s_barrier -> reg-prefetch
// loads force-drained twice/iter and 4-wave convoys with only 2 barrier
// groups/CU to cover the stalls.
// Changes (same per-stream math as R12, verified):
//  1. 1024 blocks x 128 thr (2 waves): 4 independent barrier groups/CU,
//     2-wave rendezvous.  Decode keeps id%8 = bh>>2 (XCD L2 clustering,
//     R4-measured FETCH 62.6->12.3MB).
//  2. K/V double-buffered in LDS; ONE raw s_barrier per iter:
//       compute(buf[cur]); ds_write regs->buf[cur^1]; issue loads kt+2;
//       s_waitcnt lgkmcnt(0); s_barrier; sched_barrier(0)
//     Raw barrier does NOT drain vmcnt -> prefetch loads fly across with a
//     full compute phase of flight (T4, same lesson as qkv R11).
//     Race ledger: buf[cur^1] last read at iter kt-1; that iter's lgkm(0)
//     drained the reads before its barrier -> safe to overwrite.  This
//     iter's lgkm(0)+barrier publishes writes before next iter reads.
//  3. lP -> [4][16][64] with XOR slot swizzle (slot ^= l15&7; write slot
//     sub*2+(quad>>1), read slots quad / 4+quad): bank-uniform, and total
//     LDS = 32768 (K/V dbuf) + 8192 (lP) = 40960 B -> exactly 4 blocks/CU.
// ---------------------------------------------------------------------------
static __device__ __forceinline__ void qk_step(
    const unsigned short* lK, int l15, int c0, int c1,
    short8 q0, short8 q1, floatx4 (&sc)[4]) {
#pragma unroll
  for (int sub = 0; sub < 4; ++sub) {
    const unsigned short* kr = lK + (sub * 16 + l15) * 64;
    short8 a0 = *(const short8*)(kr + c0);
    short8 a1 = *(const short8*)(kr + c1);
    floatx4 s = {0.f, 0.f, 0.f, 0.f};
    s = __builtin_amdgcn_mfma_f32_16x16x32_bf16(a0, q0, s, 0, 0, 0);
    s = __builtin_amdgcn_mfma_f32_16x16x32_bf16(a1, q1, s, 0, 0, 0);
    sc[sub] = s;
  }
}

static __device__ __forceinline__ void sm_step(
    floatx4 (&sc)[4], float& m_i, float& l_i, floatx4 (&o)[4],
    bool diag, int qin, int quad) {
  if (diag) {  // causal mask on diagonal tile: k-within > q-within
#pragma unroll
    for (int sub = 0; sub < 4; ++sub)
#pragma unroll
      for (int i = 0; i < 4; ++i)
        if (sub * 16 + quad * 4 + i > qin) sc[sub][i] = -1e30f;
  }
  float mb = sc[0][0];
#pragma unroll
  for (int sub = 0; sub < 4; ++sub)
#pragma unroll
    for (int i = 0; i < 4; ++i) mb = fmaxf(mb, sc[sub][i]);
  mb = fmaxf(mb, __shfl_xor(mb, 16));
  mb = fmaxf(mb, __shfl_xor(mb, 32));

  float mn = fmaxf(m_i, mb);
  float al = fexp2(m_i - mn);
  m_i = mn;
  float rs = 0.f;
#pragma unroll
  for (int sub = 0; sub < 4; ++sub)
#pragma unroll
    for (int i = 0; i < 4; ++i) {
      float p = fexp2(sc[sub][i] - mn);
      sc[sub][i] = p;
      rs += p;
    }
  rs += __shfl_xor(rs, 16);
  rs += __shfl_xor(rs, 32);
  l_i = l_i * al + rs;
#pragma unroll
  for (int n = 0; n < 4; ++n) {
    o[n][0] *= al; o[n][1] *= al; o[n][2] *= al; o[n][3] *= al;
  }
}

// P^T staging through XOR-swizzled lP row (q=l15), then PV MFMA.
// Write: k = sub*16+quad*4+i -> 16B slot sub*2+(quad>>1), 8B half quad&1,
// stored at slot^(l15&7).  Read: pa0 = k[quad*8..+8) -> slot quad^(l15&7);
// pa1 = k[32+quad*8..+8) -> slot (4+quad)^(l15&7).  Same-wave DS ordering
// makes the write->read turnaround barrier-free.
static __device__ __forceinline__ void pv_step(
    const floatx4 (&sc)[4], floatx4 (&o)[4], unsigned short* lPws,
    const unsigned short* lV, int l15, int quad, int c0, int c1) {
  int swz = l15 & 7;
  unsigned short* pw = lPws + l15 * 64;
#pragma unroll
  for (int sub = 0; sub < 4; ++sub) {
    uint2 w;
    w.x = pk2bf(sc[sub][0], sc[sub][1]);
    w.y = pk2bf(sc[sub][2], sc[sub][3]);
    int slot = (sub * 2 + (quad >> 1)) ^ swz;
    *(uint2*)(pw + slot * 8 + (quad & 1) * 4) = w;
  }
  short8 pa0 = *(const short8*)(pw + ((quad ^ swz) * 8));
  short8 pa1 = *(const short8*)(pw + (((4 + quad) ^ swz) * 8));
#pragma unroll
  for (int n = 0; n < 4; ++n) {
    const unsigned short* vr = lV + (n * 16 + l15) * 64;
    short8 vb0 = *(const short8*)(vr + c0);
    short8 vb1 = *(const short8*)(vr + c1);
    o[n] = __builtin_amdgcn_mfma_f32_16x16x32_bf16(vb0, pa0, o[n], 0, 0, 0);
    o[n] = __builtin_amdgcn_mfma_f32_16x16x32_bf16(vb1, pa1, o[n], 0, 0, 0);
  }
}

__global__ __launch_bounds__(128, 2) void attn_flash(
    const unsigned short* __restrict__ Q, const unsigned short* __restrict__ K,
    const unsigned short* __restrict__ Vt, unsigned short* __restrict__ Oc) {
  __shared__ __align__(16) unsigned short lK[2][64 * 64];  // [kj][d] swizzled
  __shared__ __align__(16) unsigned short lV[2][64 * 64];  // [d][kj] swizzled
  __shared__ __align__(16) unsigned short lP[4][16 * 64];  // [wave*2+stream]

  int tid = threadIdx.x;
  int wave = tid >> 6, lane = tid & 63;
  int l15 = lane & 15, quad = lane >> 4;

  // decode: id%8 = XCD = bh>>2; then bh-sub, then (pair, half)
  int id = blockIdx.x;                 // 0..1023
  int bh = (id & 7) * 4 + ((id >> 3) & 3);
  int rem = id >> 5;                   // 0..31
  int pair = rem >> 1;                 // 0..15
  int h = rem & 1;                     // which 32-row half of each tile
  int tA = pair, tB = 31 - pair;
  int NT = tB + 1;                     // kv tiles this block (17..32)

  size_t base = (size_t)bh * 2048 * 64;
  int qoff = h * 32 + wave * 16 + l15;   // q row within tile (0..63)

  // Q fragments (B-operand, loop-invariant) for both streams
  const unsigned short* qrowA = Q + base + (size_t)(tA * 64 + qoff) * 64;
  const unsigned short* qrowB = Q + base + (size_t)(tB * 64 + qoff) * 64;
  short8 qA0 = *(const short8*)(qrowA + quad * 8);
  short8 qA1 = *(const short8*)(qrowA + 32 + quad * 8);
  short8 qB0 = *(const short8*)(qrowB + quad * 8);
  short8 qB1 = *(const short8*)(qrowB + 32 + quad * 8);

  floatx4 oA[4], oB[4];
  float mA_i = -1e30f, lA_i = 0.f, mB_i = -1e30f, lB_i = 0.f;
#pragma unroll
  for (int n = 0; n < 4; ++n) {
    oA[n] = (floatx4){0.f, 0.f, 0.f, 0.f};
    oB[n] = (floatx4){0.f, 0.f, 0.f, 0.f};
  }

  // staging: 128 threads cover 64 rows x 8 chunks; this thread owns rows
  // r0+{0,16,32,48} (same &7 -> same swizzled slot sl), 16B chunk g.
  int r0 = tid >> 3, g = tid & 7;      // r0 0..15
  int e0 = g * 8;                      // global element offset of chunk g
  int sl = (g ^ (r0 & 7)) * 8;         // swizzled LDS slot (element offset)
  int fsw = l15 & 7;                   // fragment-read swizzle
  int c0 = (quad ^ fsw) * 8;           // slot of global chunk quad
  int c1 = ((quad + 4) ^ fsw) * 8;     // slot of global chunk quad+4

  short8 pk0, pk1, pk2, pk3, pv0, pv1, pv2, pv3;

  // prologue: load kt=0, write buf0, issue loads kt=1 (fly across barrier)
  {
    const unsigned short* kp = K + base;
    const unsigned short* vp = Vt + base;
    pk0 = *(const short8*)(kp + (r0 +  0) * 64 + e0);
    pk1 = *(const short8*)(kp + (r0 + 16) * 64 + e0);
    pk2 = *(const short8*)(kp + (r0 + 32) * 64 + e0);
    pk3 = *(const short8*)(kp + (r0 + 48) * 64 + e0);
    pv0 = *(const short8*)(vp + (size_t)(r0 +  0) * 2048 + e0);
    pv1 = *(const short8*)(vp + (size_t)(r0 + 16) * 2048 + e0);
    pv2 = *(const short8*)(vp + (size_t)(r0 + 32) * 2048 + e0);
    pv3 = *(const short8*)(vp + (size_t)(r0 + 48) * 2048 + e0);
  }
  *(short8*)(lK[0] + (r0 +  0) * 64 + sl) = pk0;
  *(short8*)(lK[0] + (r0 + 16) * 64 + sl) = pk1;
  *(short8*)(lK[0] + (r0 + 32) * 64 + sl) = pk2;
  *(short8*)(lK[0] + (r0 + 48) * 64 + sl) = pk3;
  *(short8*)(lV[0] + (r0 +  0) * 64 + sl) = pv0;
  *(short8*)(lV[0] + (r0 + 16) * 64 + sl) = pv1;
  *(short8*)(lV[0] + (r0 + 32) * 64 + sl) = pv2;
  *(short8*)(lV[0] + (r0 + 48) * 64 + sl) = pv3;
  {  // NT >= 17, kt=1 always exists
    const unsigned short* kp = K + base + 4096;
    const unsigned short* vp = Vt + base + 64;
    pk0 = *(const short8*)(kp + (r0 +  0) * 64 + e0);
    pk1 = *(const short8*)(kp + (r0 + 16) * 64 + e0);
    pk2 = *(const short8*)(kp + (r0 + 32) * 64 + e0);
    pk3 = *(const short8*)(kp + (r0 + 48) * 64 + e0);
    pv0 = *(const short8*)(vp + (size_t)(r0 +  0) * 2048 + e0);
    pv1 = *(const short8*)(vp + (size_t)(r0 + 16) * 2048 + e0);
    pv2 = *(const short8*)(vp + (size_t)(r0 + 32) * 2048 + e0);
    pv3 = *(const short8*)(vp + (size_t)(r0 + 48) * 2048 + e0);
  }
  asm volatile("s_waitcnt lgkmcnt(0)" ::: "memory");
  __builtin_amdgcn_s_barrier();
  __builtin_amdgcn_sched_barrier(0);

  int qin = qoff;

  for (int kt = 0; kt < NT; ++kt) {
    int cur = kt & 1;
    bool aAct = (kt <= tA);
    const unsigned short* lKc = lK[cur];
    const unsigned short* lVc = lV[cur];

    // ---- dual-stream compute: B always, A while kt <= tA
    floatx4 scB[4], scA[4];
    qk_step(lKc, l15, c0, c1, qB0, qB1, scB);
    if (aAct) qk_step(lKc, l15, c0, c1, qA0, qA1, scA);

    sm_step(scB, mB_i, lB_i, oB, kt == NT - 1, qin, quad);
    if (aAct) sm_step(scA, mA_i, lA_i, oA, kt == tA, qin, quad);

    pv_step(scB, oB, lP[wave * 2], lVc, l15, quad, c0, c1);
    if (aAct) pv_step(scA, oA, lP[wave * 2 + 1], lVc, l15, quad, c0, c1);

    if (kt + 1 < NT) {
      // write next tile (regs hold kt+1 data) into the other buffer
      unsigned short* wK = lK[cur ^ 1];
      unsigned short* wV = lV[cur ^ 1];
      *(short8*)(wK + (r0 +  0) * 64 + sl) = pk0;
      *(short8*)(wK + (r0 + 16) * 64 + sl) = pk1;
      *(short8*)(wK + (r0 + 32) * 64 + sl) = pk2;
      *(short8*)(wK + (r0 + 48) * 64 + sl) = pk3;
      *(short8*)(wV + (r0 +  0) * 64 + sl) = pv0;
      *(short8*)(wV + (r0 + 16) * 64 + sl) = pv1;
      *(short8*)(wV + (r0 + 32) * 64 + sl) = pv2;
      *(short8*)(wV + (r0 + 48) * 64 + sl) = pv3;
      if (kt + 2 < NT) {  // issue loads for kt+2; consumed end of next iter
        const unsigned short* kp = K + base + (size_t)(kt + 2) * 4096;
        const unsigned short* vp = Vt + base + (size_t)(kt + 2) * 64;
        pk0 = *(const short8*)(kp + (r0 +  0) * 64 + e0);
        pk1 = *(const short8*)(kp + (r0 + 16) * 64 + e0);
        pk2 = *(const short8*)(kp + (r0 + 32) * 64 + e0);
        pk3 = *(const short8*)(kp + (r0 + 48) * 64 + e0);
        pv0 = *(const short8*)(vp + (size_t)(r0 +  0) * 2048 + e0);
        pv1 = *(const short8*)(vp + (size_t)(r0 + 16) * 2048 + e0);
        pv2 = *(const short8*)(vp + (size_t)(r0 + 32) * 2048 + e0);
        pv3 = *(const short8*)(vp + (size_t)(r0 + 48) * 2048 + e0);
      }
      // drain my ds reads+writes, then raw barrier (vmcnt NOT drained:
      // the kt+2 loads stay in flight across it)
      asm volatile("s_waitcnt lgkmcnt(0)" ::: "memory");
      __builtin_amdgcn_s_barrier();
      __builtin_amdgcn_sched_barrier(0);
    }
  }

  // ---- epilogue: per-lane 1/l, packed b64 stores for both streams
  int b = bh >> 4, hh = bh & 15;
  {
    float inv = 1.f / lB_i;
    int s = tB * 64 + qoff;
    size_t orow = (size_t)(b * 2048 + s) * 1024 + hh * 64;
#pragma unroll
    for (int n = 0; n < 4; ++n) {
      uint2 ov;
      ov.x = pk2bf(oB[n][0] * inv, oB[n][1] * inv);
      ov.y = pk2bf(oB[n][2] * inv, oB[n][3] * inv);
      *(uint2*)(Oc + orow + n * 16 + quad * 4) = ov;
    }
  }
  {
    float inv = 1.f / lA_i;
    int s = tA * 64 + qoff;
    size_t orow = (size_t)(b * 2048 + s) * 1024 + hh * 64;
#pragma unroll
    for (int n = 0; n < 4; ++n) {
      uint2 ov;
      ov.x = pk2bf(oA[n][0] * inv, oA[n][1] * inv);
      ov.y = pk2bf(oA[n][2] * inv, oA[n][3] * inv);
      *(uint2*)(Oc + orow + n * 16 + quad * 4) = ov;
    }
  }
}

// ---------------------------------------------------------------------------
extern "C" void kernel_launch(void* const* d_in, const int* in_sizes, int n_in,
                              void* d_out, int out_size, void* d_ws, size_t ws_size,
                              hipStream_t stream) {
  const float* x  = (const float*)d_in[0];
  const int* tokpos = (const int*)d_in[1];
  const float* Wq = (const float*)d_in[2];
  const float* Wk = (const float*)d_in[3];
  const float* Wv = (const float*)d_in[4];
  const float* Wo = (const float*)d_in[5];
  float* out = (float*)d_out;

  float* ws = (float*)d_ws;
  float* ctab = ws;
  float* stab = ctab + 65536;
  unsigned short* u = (unsigned short*)(stab + 65536);
  unsigned short* Qb  = u;
  unsigned short* Kb  = Qb + 4194304;
  unsigned short* Vb  = Kb + 4194304;   // transposed [bh][d][s]
  unsigned short* Oc  = Vb + 4194304;
  unsigned short* xb  = Oc + 4194304;
  unsigned short* Wqb = xb + 4194304;
  unsigned short* Wkb = Wqb + 1048576;
  unsigned short* Wvb = Wkb + 1048576;
  unsigned short* Wob = Wvb + 1048576;

  cvt_all<<<dim3(4096, 6), 256, 0, stream>>>(
      (const float4*)x, (const float4*)Wq, (const float4*)Wk,
      (const float4*)Wv, (const float4*)Wo,
      (ushort4*)xb, (ushort4*)Wqb, (ushort4*)Wkb, (ushort4*)Wvb, (ushort4*)Wob,
      tokpos, ctab, stab);

  qkv_mfma<<<dim3(64, 8, 3), 256, 0, stream>>>(
      xb, Wqb, Wkb, Wvb, ctab, stab, Qb, Kb, Vb);
  attn_flash<<<dim3(1024), 128, 0, stream>>>(Qb, Kb, Vb, Oc);
  oproj_mfma<<<dim3(64, 8), 256, 0, stream>>>(Oc, Wob, out);
}